// Round 7
// baseline (947.365 us; speedup 1.0000x reference)
//
#include <hip/hip_runtime.h>
#include <hip/hip_bf16.h>
#include <math.h>

// Problem dims (fixed by the reference)
#define DD 1024
#define HH 4096
#define TT 8192

typedef __attribute__((ext_vector_type(4))) float f32x4;
typedef __attribute__((ext_vector_type(8))) __bf16 bf16x8;
typedef __attribute__((ext_vector_type(4))) __bf16 bf16x4;

__device__ __forceinline__ ushort f2bf(float f) {
    union { float f; unsigned u; } v; v.f = f;
    unsigned r = v.u + 0x7FFFu + ((v.u >> 16) & 1u);   // RNE
    return (ushort)(r >> 16);
}
__device__ __forceinline__ float clip1(float v){ return fminf(fmaxf(v, -1.f), 1.f); }
__device__ __forceinline__ float clip5(float v){ return fminf(fmaxf(v, -5.f), 5.f); }
__device__ __forceinline__ int fr3(int r){ return ((r >> 1) ^ (r >> 3)) & 7; }

__device__ __forceinline__ void gload_lds16(const void* g, void* l) {
    __builtin_amdgcn_global_load_lds((const __attribute__((address_space(1))) void*)g,
                                     (__attribute__((address_space(3))) void*)l, 16, 0, 0);
}

template<int N> __device__ __forceinline__ void vmwait() {
    if      constexpr (N == 0)  asm volatile("s_waitcnt vmcnt(0)" ::: "memory");
    else if constexpr (N == 2)  asm volatile("s_waitcnt vmcnt(2)" ::: "memory");
    else if constexpr (N == 4)  asm volatile("s_waitcnt vmcnt(4)" ::: "memory");
    else if constexpr (N == 6)  asm volatile("s_waitcnt vmcnt(6)" ::: "memory");
    else if constexpr (N == 12) asm volatile("s_waitcnt vmcnt(12)" ::: "memory");
}

// in-register elementwise powers of a bf16x8 fragment (via f32)
__device__ __forceinline__ bf16x8 sq8(bf16x8 a) {
    bf16x8 r;
    #pragma unroll
    for (int j = 0; j < 8; ++j) { const float f = (float)a[j]; r[j] = (__bf16)(f * f); }
    return r;
}
__device__ __forceinline__ bf16x8 cb8(bf16x8 a) {
    bf16x8 r;
    #pragma unroll
    for (int j = 0; j < 8; ++j) { const float f = (float)a[j]; r[j] = (__bf16)(f * f * f); }
    return r;
}

// ---- pack coeff [N,4,DIN] fp32 -> B^T bf16 [N][3*DIN] (clip); k=0 slice -> bias[N]
template<int DIN>
__global__ __launch_bounds__(256) void pack_b(const float* __restrict__ c,
                                              ushort* __restrict__ Bp,
                                              float* __restrict__ bias) {
    const int n = blockIdx.x;
    const float* src = c + (size_t)n * 4 * DIN;
    ushort* dst = Bp + (size_t)n * 3 * DIN;
    float bsum = 0.f;
    for (int d = threadIdx.x; d < DIN; d += 256) {
        bsum += clip1(src[d]);
        dst[d]         = f2bf(clip1(src[DIN + d]));
        dst[DIN + d]   = f2bf(clip1(src[2*DIN + d]));
        dst[2*DIN + d] = f2bf(clip1(src[3*DIN + d]));
    }
    #pragma unroll
    for (int off = 32; off > 0; off >>= 1) bsum += __shfl_down(bsum, off, 64);
    __shared__ float red[4];
    const int wave = threadIdx.x >> 6, lane = threadIdx.x & 63;
    if (lane == 0) red[wave] = bsum;
    __syncthreads();
    if (threadIdx.x == 0) bias[n] = red[0] + red[1] + red[2] + red[3];
}

// ---- 256-row bf16 MFMA GEMM, BK=64, 8 waves, counted-vmcnt, in-register powers.
// As: single v-plane [256][64] bf16 (reg-staged, fr3-swizzled). A-frags read ONCE
// per iter (phase 0) and kept; phase1 = sq8(af0), phase2 = cb8(af0) in-register.
// B: 3-slot ring [BN][64] (slot == power), DMA'd via pre-swizzled global source.
// EPI=1: 256x256, src x fp32; C -> *0.1+bias, clip5, gelu, clip5 -> g bf16 [T][H]
// EPI=2: 256x128, src g bf16; C -> *0.1+bias, clip5, +resid -> y fp32 [T][D]
template<int EPI>
__global__ __launch_bounds__(512, 2) void gemm_k(
    const void* __restrict__ Asrc, const __bf16* __restrict__ Bt,
    const float* __restrict__ bias,
    __bf16* __restrict__ gout,
    const float* __restrict__ resid, float* __restrict__ yout)
{
    constexpr int SD    = (EPI == 1) ? DD : HH;   // source width (one power group)
    constexpr int K     = 3 * SD;
    constexpr int NIT   = SD / 64;
    constexpr int BN    = (EPI == 1) ? 256 : 128;
    constexpr int NF    = (EPI == 1) ? 8 : 4;     // n-frags per wave (wave tile 64 x NF*16)
    constexpr int BL    = (EPI == 1) ? 4 : 2;     // B loads/slot/thread
    constexpr int XL    = (EPI == 1) ? 8 : 4;     // A-source loads/thread
    constexpr int BSLOT = BN * 128;               // bytes per B slot ([BN][64] bf16)

    __shared__ char LB[3*BSLOT + 32768];          // EPI1: 128KB, EPI2: 80KB
    char* BsB = LB;
    char* AsB = LB + 3*BSLOT;

    const int tid  = threadIdx.x;
    const int lane = tid & 63;
    const int wave = tid >> 6;
    const int wrow = wave >> 1, wcol = wave & 1;  // 4x2 waves; wave tile 64 x NF*16
    const int m0 = blockIdx.y * 256, n0 = blockIdx.x * BN;
    const int ln15 = lane & 15, l4 = lane >> 4;

    // fr3-swizzled frag-read byte offsets (kc=1 -> addr ^ 64)
    int aoff[4], boff[NF];
    #pragma unroll
    for (int m = 0; m < 4; ++m) {
        const int r = wrow*64 + m*16 + ln15;
        aoff[m] = r*128 + ((l4 ^ fr3(r)) << 4);
    }
    #pragma unroll
    for (int n = 0; n < NF; ++n) {
        const int r = wcol*(NF*16) + n*16 + ln15;
        boff[n] = r*128 + ((l4 ^ fr3(r)) << 4);
    }

    f32x4 acc[4][NF];
    #pragma unroll
    for (int m = 0; m < 4; ++m)
        #pragma unroll
        for (int n = 0; n < NF; ++n)
            acc[m][n] = (f32x4){0.f, 0.f, 0.f, 0.f};

    // B tile DMA: [BN][64] bf16; LDS dest linear, global source pre-swizzled
    auto issueB = [&](int kcol, int slot) {
        char* dst = BsB + slot * BSLOT;
        #pragma unroll
        for (int it = 0; it < BL; ++it) {
            const int c = it*512 + tid, row = c >> 3, ch = c & 7;
            gload_lds16(Bt + (size_t)(n0 + row) * K + kcol + ((ch ^ fr3(row)) << 3),
                        dst + (size_t)c * 16);
        }
    };

    // A-source prefetch registers ([256][64] window)
    f32x4  xw[8];   // EPI==1
    bf16x8 gw[4];   // EPI==2

    auto issueX = [&](int i) {
        if constexpr (EPI == 1) {
            const float* X = (const float*)Asrc;
            #pragma unroll
            for (int k = 0; k < 8; ++k) {
                const int row = k*32 + (tid >> 4), q = tid & 15;
                xw[k] = *reinterpret_cast<const f32x4*>(
                    X + (size_t)(m0 + row) * DD + 64*i + q*4);
            }
        } else {
            const __bf16* G = (const __bf16*)Asrc;
            #pragma unroll
            for (int k = 0; k < 4; ++k) {
                const int row = k*64 + (tid >> 3), ch = tid & 7;
                gw[k] = *reinterpret_cast<const bf16x8*>(
                    G + (size_t)(m0 + row) * HH + 64*i + ch*8);
            }
        }
    };

    // write the v-plane (swizzled). EPI1: clip+cvt; EPI2: raw copy (no VALU)
    auto powers = [&]() {
        if constexpr (EPI == 1) {
            #pragma unroll
            for (int k = 0; k < 8; ++k) {
                const int row = k*32 + (tid >> 4), q = tid & 15;
                bf16x4 u;
                #pragma unroll
                for (int j = 0; j < 4; ++j) u[j] = (__bf16)clip5(xw[k][j]);
                *reinterpret_cast<bf16x4*>(AsB + row*128
                    + (((q >> 1) ^ fr3(row)) << 4) + (q & 1)*8) = u;
            }
        } else {
            #pragma unroll
            for (int k = 0; k < 4; ++k) {
                const int row = k*64 + (tid >> 3), ch = tid & 7;
                *reinterpret_cast<bf16x8*>(AsB + row*128
                    + ((ch ^ fr3(row)) << 4)) = gw[k];
            }
        }
    };

    bf16x8 af0[4][2];
    auto loadA = [&]() {
        #pragma unroll
        for (int m = 0; m < 4; ++m)
            #pragma unroll
            for (int kc = 0; kc < 2; ++kc)
                af0[m][kc] = *reinterpret_cast<const bf16x8*>(AsB + (aoff[m] ^ (kc << 6)));
    };

    auto mfma_phase = [&](int p, int slot) {
        const char* Bs_ = BsB + slot * BSLOT;
        #pragma unroll
        for (int kc = 0; kc < 2; ++kc) {
            bf16x8 a_[4];
            #pragma unroll
            for (int m = 0; m < 4; ++m) {
                if (p == 0)      a_[m] = af0[m][kc];
                else if (p == 1) a_[m] = sq8(af0[m][kc]);
                else             a_[m] = cb8(af0[m][kc]);
            }
            #pragma unroll
            for (int nb = 0; nb < NF; nb += 4) {
                bf16x8 b_[4];
                #pragma unroll
                for (int n = 0; n < 4; ++n)
                    b_[n] = *reinterpret_cast<const bf16x8*>(Bs_ + (boff[nb+n] ^ (kc << 6)));
                __builtin_amdgcn_s_setprio(1);
                #pragma unroll
                for (int m = 0; m < 4; ++m)
                    #pragma unroll
                    for (int n = 0; n < 4; ++n)
                        acc[m][nb+n] = __builtin_amdgcn_mfma_f32_16x16x32_bf16(
                            a_[m], b_[n], acc[m][nb+n], 0, 0, 0);
                __builtin_amdgcn_s_setprio(0);
            }
        }
    };

    // ---- prologue
    issueB(0, 0);          // p0, iter0 -> slot0
    issueB(SD, 1);         // p1, iter0 -> slot1
    issueX(0);
    powers();              // compiler auto-waits xw/gw (drains older B loads too)
    asm volatile("s_waitcnt lgkmcnt(0)" ::: "memory");

    for (int i = 0; i < NIT; ++i) {
        const bool nl = (i + 1 < NIT);
        const int d0 = 64*i, d1 = d0 + 64;
        // ---- phase 0 (v, slot 0): As just (re)written -> frag reads
        vmwait<BL>();
        asm volatile("s_waitcnt lgkmcnt(0)" ::: "memory");
        __builtin_amdgcn_s_barrier();
        asm volatile("" ::: "memory");
        issueB(2*SD + d0, 2);                  // this iter's p2 tile
        loadA();
        mfma_phase(0, 0);
        // ---- phase 1 (v^2, slot 1)
        vmwait<BL>();
        __builtin_amdgcn_s_barrier();
        asm volatile("" ::: "memory");
        if (nl) { issueB(d1, 0); issueX(i+1); }
        mfma_phase(1, 1);
        // ---- phase 2 (v^3, slot 2)
        if (nl) vmwait<BL + XL>(); else vmwait<0>();
        __builtin_amdgcn_s_barrier();
        asm volatile("" ::: "memory");
        if (nl) issueB(SD + d1, 1);
        mfma_phase(2, 2);
        if (nl) powers();                      // overlapped; drains via next ph0 lgkmcnt
    }

    // epilogue — C/D map: col = lane&15, row = (lane>>4)*4 + reg  [m89-verified]
    float bn[NF];
    #pragma unroll
    for (int n = 0; n < NF; ++n) bn[n] = bias[n0 + wcol*(NF*16) + n*16 + ln15];

    #pragma unroll
    for (int m = 0; m < 4; ++m) {
        #pragma unroll
        for (int j = 0; j < 4; ++j) {
            const int gm = m0 + wrow*64 + m*16 + l4*4 + j;
            #pragma unroll
            for (int n = 0; n < NF; ++n) {
                const int gn = n0 + wcol*(NF*16) + n*16 + ln15;
                float v = 0.1f * (acc[m][n][j] + bn[n]);
                v = clip5(v);
                if (EPI == 1) {
                    float g = 0.5f * v * (1.f + erff(v * 0.70710678118654752f));
                    g = clip5(g);
                    gout[(size_t)gm * HH + gn] = (__bf16)g;
                } else {
                    yout[(size_t)gm * DD + gn] = v + resid[(size_t)gm * DD + gn];
                }
            }
        }
    }
}

// ---- row LayerNorm over D=1024, in-place, one block per row
__global__ __launch_bounds__(256) void ln_k(float* y,
                                            const float* __restrict__ gamma,
                                            const float* __restrict__ beta) {
    const int t = blockIdx.x, tid = threadIdx.x;
    const float4 v = reinterpret_cast<const float4*>(y + (size_t)t * DD)[tid];
    float s  = v.x + v.y + v.z + v.w;
    float s2 = v.x*v.x + v.y*v.y + v.z*v.z + v.w*v.w;
    #pragma unroll
    for (int off = 32; off > 0; off >>= 1) {
        s  += __shfl_down(s,  off, 64);
        s2 += __shfl_down(s2, off, 64);
    }
    __shared__ float rs[4], rs2[4];
    const int wave = tid >> 6, lane = tid & 63;
    if (lane == 0) { rs[wave] = s; rs2[wave] = s2; }
    __syncthreads();
    s  = rs[0] + rs[1] + rs[2] + rs[3];
    s2 = rs2[0] + rs2[1] + rs2[2] + rs2[3];
    const float mu  = s * (1.f / DD);
    const float var = s2 * (1.f / DD) - mu * mu;
    const float inv = rsqrtf(var + 1e-5f);
    const float4 g = reinterpret_cast<const float4*>(gamma)[tid];
    const float4 b = reinterpret_cast<const float4*>(beta)[tid];
    float4 o;
    o.x = (v.x - mu) * inv * g.x + b.x;
    o.y = (v.y - mu) * inv * g.y + b.y;
    o.z = (v.z - mu) * inv * g.z + b.z;
    o.w = (v.w - mu) * inv * g.w + b.w;
    reinterpret_cast<float4*>(y + (size_t)t * DD)[tid] = o;
}

extern "C" void kernel_launch(void* const* d_in, const int* in_sizes, int n_in,
                              void* d_out, int out_size, void* d_ws, size_t ws_size,
                              hipStream_t stream) {
    const float* x     = (const float*)d_in[0];
    const float* c1    = (const float*)d_in[1];
    const float* c2    = (const float*)d_in[2];
    const float* gamma = (const float*)d_in[3];
    const float* beta  = (const float*)d_in[4];
    float* out = (float*)d_out;

    // compact workspace: peak ~88 MiB
    char* ws = (char*)d_ws;
    const size_t OFF_G     = 0;            // g bf16 [TT][HH] = 67,108,864
    const size_t OFF_B     = 67108864;     // B1p/B2p shared (sequential liveness)
    const size_t OFF_BIAS1 = 92274688;     // HH*4
    const size_t OFF_BIAS2 = 92291072;     // DD*4

    __bf16* gbuf  = (__bf16*)(ws + OFF_G);
    ushort* B1p   = (ushort*)(ws + OFF_B);
    ushort* B2p   = (ushort*)(ws + OFF_B);
    float*  bias1 = (float*) (ws + OFF_BIAS1);
    float*  bias2 = (float*) (ws + OFF_BIAS2);

    pack_b<DD><<<HH, 256, 0, stream>>>(c1, B1p, bias1);
    gemm_k<1><<<dim3(HH / 256, TT / 256), 512, 0, stream>>>(
        (const void*)x, (const __bf16*)B1p, bias1, gbuf, nullptr, nullptr);
    pack_b<HH><<<DD, 256, 0, stream>>>(c2, B2p, bias2);      // reuses B region after GEMM1
    gemm_k<2><<<dim3(DD / 128, TT / 256), 512, 0, stream>>>(
        (const void*)gbuf, (const __bf16*)B2p, bias2, nullptr, x, (float*)out);
    ln_k<<<TT, 256, 0, stream>>>(out, gamma, beta);
}

// Round 8
// 603.547 us; speedup vs baseline: 1.5697x; 1.5697x over previous
//
#include <hip/hip_runtime.h>
#include <hip/hip_bf16.h>
#include <math.h>

// Problem dims (fixed by the reference)
#define DD 1024
#define HH 4096
#define TT 8192

typedef __attribute__((ext_vector_type(4))) float f32x4;
typedef __attribute__((ext_vector_type(8))) __bf16 bf16x8;
typedef __attribute__((ext_vector_type(4))) __bf16 bf16x4;

__device__ __forceinline__ ushort f2bf(float f) {
    union { float f; unsigned u; } v; v.f = f;
    unsigned r = v.u + 0x7FFFu + ((v.u >> 16) & 1u);   // RNE
    return (ushort)(r >> 16);
}
__device__ __forceinline__ float clip1(float v){ return fminf(fmaxf(v, -1.f), 1.f); }
__device__ __forceinline__ float clip5(float v){ return fminf(fmaxf(v, -5.f), 5.f); }
__device__ __forceinline__ int frow(int r){ return (r >> 1) & 3; }   // 64B-row swizzle

__device__ __forceinline__ void gload_lds16(const void* g, void* l) {
    __builtin_amdgcn_global_load_lds((const __attribute__((address_space(1))) void*)g,
                                     (__attribute__((address_space(3))) void*)l, 16, 0, 0);
}

template<int N> __device__ __forceinline__ void vmwait() {
    if      constexpr (N == 0)  asm volatile("s_waitcnt vmcnt(0)" ::: "memory");
    else if constexpr (N == 3)  asm volatile("s_waitcnt vmcnt(3)" ::: "memory");
    else if constexpr (N == 6)  asm volatile("s_waitcnt vmcnt(6)" ::: "memory");
}

// in-register elementwise powers of a bf16x8 fragment (via f32)
__device__ __forceinline__ bf16x8 sq8(bf16x8 a) {
    bf16x8 r;
    #pragma unroll
    for (int j = 0; j < 8; ++j) { const float f = (float)a[j]; r[j] = (__bf16)(f * f); }
    return r;
}
__device__ __forceinline__ bf16x8 cb8(bf16x8 a) {
    bf16x8 r;
    #pragma unroll
    for (int j = 0; j < 8; ++j) { const float f = (float)a[j]; r[j] = (__bf16)(f * f * f); }
    return r;
}

// ---- pack coeff [N,4,DIN] fp32 -> B^T bf16 [N][3*DIN] (clip); k=0 slice -> bias[N]
template<int DIN>
__global__ __launch_bounds__(256) void pack_b(const float* __restrict__ c,
                                              ushort* __restrict__ Bp,
                                              float* __restrict__ bias) {
    const int n = blockIdx.x;
    const float* src = c + (size_t)n * 4 * DIN;
    ushort* dst = Bp + (size_t)n * 3 * DIN;
    float bsum = 0.f;
    for (int d = threadIdx.x; d < DIN; d += 256) {
        bsum += clip1(src[d]);
        dst[d]         = f2bf(clip1(src[DIN + d]));
        dst[DIN + d]   = f2bf(clip1(src[2*DIN + d]));
        dst[2*DIN + d] = f2bf(clip1(src[3*DIN + d]));
    }
    #pragma unroll
    for (int off = 32; off > 0; off >>= 1) bsum += __shfl_down(bsum, off, 64);
    __shared__ float red[4];
    const int wave = threadIdx.x >> 6, lane = threadIdx.x & 63;
    if (lane == 0) red[wave] = bsum;
    __syncthreads();
    if (threadIdx.x == 0) bias[n] = red[0] + red[1] + red[2] + red[3];
}

// ---- 256-row bf16 MFMA GEMM, BK=32, ONE barrier per 96-K iteration.
// As: v-plane only [256][32] bf16, double-buffered, swizzled; powers of A
// computed in-register per-m (transient 8 regs) at each of 3 power phases.
// B: 6-slot ring (2 iters x 3 powers); all 3 tiles of iter i+1 staged during
// iter i's mega-phase via pre-swizzled-source global_load_lds.
// EPI=1: 256x256, src x fp32; C -> *0.1+bias, clip5, gelu, clip5 -> g bf16 [T][H]
// EPI=2: 256x128, src g bf16; C -> *0.1+bias, clip5, +resid -> y fp32 [T][D]
template<int EPI>
__global__ __launch_bounds__(512, 2) void gemm_k(
    const void* __restrict__ Asrc, const __bf16* __restrict__ Bt,
    const float* __restrict__ bias,
    __bf16* __restrict__ gout,
    const float* __restrict__ resid, float* __restrict__ yout)
{
    constexpr int SD    = (EPI == 1) ? DD : HH;   // source width (one power group)
    constexpr int K     = 3 * SD;
    constexpr int NIT   = SD / 32;
    constexpr int BN    = (EPI == 1) ? 256 : 128;
    constexpr int MF    = (EPI == 1) ? 8 : 4;     // m-frags per wave
    constexpr int NF    = 4;                       // n-frags per wave
    constexpr int WN    = (EPI == 1) ? 4 : 2;     // waves along N
    constexpr int BL    = (EPI == 1) ? 2 : 1;     // B loads per slot per thread
    constexpr int B3    = 3 * BL;                 // B loads per iter per thread
    constexpr int BSLOT = BN * 64;                // bytes per B slot ([BN][32] bf16)
    constexpr int ASZ   = 16384;                  // one As buffer ([256][32] bf16)

    __shared__ char LB[6*BSLOT + 2*ASZ];          // EPI1: 128KB, EPI2: 80KB
    char* BsB = LB;
    char* AsB = LB + 6*BSLOT;

    const int tid  = threadIdx.x;
    const int lane = tid & 63;
    const int wave = tid >> 6;
    const int wrow = wave / WN, wcol = wave % WN;
    const int m0 = blockIdx.y * 256, n0 = blockIdx.x * BN;
    const int ln15 = lane & 15, l4 = lane >> 4;

    // swizzled frag-read byte offsets (64B rows: chunk ^= (row>>1)&3)
    int aoff[MF], boff[NF];
    #pragma unroll
    for (int m = 0; m < MF; ++m) {
        const int r = wrow*(MF*16) + m*16 + ln15;
        aoff[m] = r*64 + ((l4 ^ frow(r)) << 4);
    }
    #pragma unroll
    for (int n = 0; n < NF; ++n) {
        const int r = wcol*(NF*16) + n*16 + ln15;
        boff[n] = r*64 + ((l4 ^ frow(r)) << 4);
    }

    f32x4 acc[MF][NF];
    #pragma unroll
    for (int m = 0; m < MF; ++m)
        #pragma unroll
        for (int n = 0; n < NF; ++n)
            acc[m][n] = (f32x4){0.f, 0.f, 0.f, 0.f};

    // stage all 3 power-tiles of K-window i into slot group pb (0 or 1)
    auto issueB3 = [&](int i, int pb) {
        #pragma unroll
        for (int s = 0; s < 3; ++s) {
            char* dst = BsB + (pb*3 + s) * BSLOT;
            const int kcol = s*SD + 32*i;
            #pragma unroll
            for (int it = 0; it < BL; ++it) {
                const int c = it*512 + tid, row = c >> 2, ch = c & 3;
                gload_lds16(Bt + (size_t)(n0 + row) * K + kcol + ((ch ^ frow(row)) << 3),
                            dst + (size_t)c * 16);
            }
        }
    };

    // A-source prefetch registers (one [256][32] window; thread: row=t>>1, half=t&1)
    f32x4  xw[4];   // EPI==1 (fp32 x)
    bf16x8 gw[2];   // EPI==2 (bf16 g)
    const int arow = tid >> 1, ahalf = tid & 1;

    auto issueX = [&](int i) {
        if constexpr (EPI == 1) {
            const float* X = (const float*)Asrc + (size_t)(m0 + arow) * DD + 32*i + ahalf*16;
            #pragma unroll
            for (int q = 0; q < 4; ++q) xw[q] = *reinterpret_cast<const f32x4*>(X + q*4);
        } else {
            const __bf16* G = (const __bf16*)Asrc + (size_t)(m0 + arow) * HH + 32*i + ahalf*16;
            #pragma unroll
            for (int q = 0; q < 2; ++q) gw[q] = *reinterpret_cast<const bf16x8*>(G + q*8);
        }
    };

    // write v-plane (swizzled). EPI1: clip+cvt; EPI2: raw copy
    auto powers = [&](int pb) {
        char* Ab = AsB + pb * ASZ;
        const int fr = frow(arow);
        if constexpr (EPI == 1) {
            bf16x8 u0, u1;
            #pragma unroll
            for (int j = 0; j < 4; ++j) {
                u0[j]   = (__bf16)clip5(xw[0][j]);
                u0[j+4] = (__bf16)clip5(xw[1][j]);
                u1[j]   = (__bf16)clip5(xw[2][j]);
                u1[j+4] = (__bf16)clip5(xw[3][j]);
            }
            *reinterpret_cast<bf16x8*>(Ab + arow*64 + (((2*ahalf)   ^ fr) << 4)) = u0;
            *reinterpret_cast<bf16x8*>(Ab + arow*64 + (((2*ahalf+1) ^ fr) << 4)) = u1;
        } else {
            *reinterpret_cast<bf16x8*>(Ab + arow*64 + (((2*ahalf)   ^ fr) << 4)) = gw[0];
            *reinterpret_cast<bf16x8*>(Ab + arow*64 + (((2*ahalf+1) ^ fr) << 4)) = gw[1];
        }
    };

    // one power phase: B-frags for slot, per-m transient A-frag with in-reg power
    auto mfma_phase = [&](const char* Ab, int p, int slot) {
        const char* Bs_ = BsB + slot * BSLOT;
        bf16x8 b_[NF];
        #pragma unroll
        for (int n = 0; n < NF; ++n)
            b_[n] = *reinterpret_cast<const bf16x8*>(Bs_ + boff[n]);
        #pragma unroll
        for (int m = 0; m < MF; ++m) {
            bf16x8 a_ = *reinterpret_cast<const bf16x8*>(Ab + aoff[m]);
            if (p == 1) a_ = sq8(a_);
            else if (p == 2) a_ = cb8(a_);
            __builtin_amdgcn_s_setprio(1);
            #pragma unroll
            for (int n = 0; n < NF; ++n)
                acc[m][n] = __builtin_amdgcn_mfma_f32_16x16x32_bf16(a_, b_[n], acc[m][n], 0, 0, 0);
            __builtin_amdgcn_s_setprio(0);
        }
    };

    // ---- prologue: X first (so powers' implicit wait is counted), then B
    issueX(0);
    issueB3(0, 0);
    powers(0);                                   // waits xw/gw only (vmcnt=B3 kept in flight)
    asm volatile("s_waitcnt lgkmcnt(0)" ::: "memory");

    for (int i = 0; i < NIT; ++i) {
        const bool nl = (i + 1 < NIT);
        const int pb = i & 1, qb = (i + 1) & 1;
        vmwait<0>();                             // B3(i): issued a full mega-phase ago
        __builtin_amdgcn_s_barrier();
        asm volatile("" ::: "memory");
        if (nl) { issueX(i+1); issueB3(i+1, qb); }
        const char* Ab = AsB + pb * ASZ;
        mfma_phase(Ab, 0, pb*3 + 0);
        mfma_phase(Ab, 1, pb*3 + 1);
        mfma_phase(Ab, 2, pb*3 + 2);
        if (nl) powers(qb);                      // counted wait (B3 stays in flight)
        asm volatile("s_waitcnt lgkmcnt(0)" ::: "memory");   // own ds_writes pre-barrier
    }

    // epilogue — C/D map: col = lane&15, row = (lane>>4)*4 + reg  [m89-verified]
    float bn[NF];
    #pragma unroll
    for (int n = 0; n < NF; ++n) bn[n] = bias[n0 + wcol*(NF*16) + n*16 + ln15];

    #pragma unroll
    for (int m = 0; m < MF; ++m) {
        #pragma unroll
        for (int j = 0; j < 4; ++j) {
            const int gm = m0 + wrow*(MF*16) + m*16 + l4*4 + j;
            #pragma unroll
            for (int n = 0; n < NF; ++n) {
                const int gn = n0 + wcol*(NF*16) + n*16 + ln15;
                float v = 0.1f * (acc[m][n][j] + bn[n]);
                v = clip5(v);
                if (EPI == 1) {
                    float g = 0.5f * v * (1.f + erff(v * 0.70710678118654752f));
                    g = clip5(g);
                    gout[(size_t)gm * HH + gn] = (__bf16)g;
                } else {
                    yout[(size_t)gm * DD + gn] = v + resid[(size_t)gm * DD + gn];
                }
            }
        }
    }
}

// ---- row LayerNorm over D=1024, in-place, one block per row
__global__ __launch_bounds__(256) void ln_k(float* y,
                                            const float* __restrict__ gamma,
                                            const float* __restrict__ beta) {
    const int t = blockIdx.x, tid = threadIdx.x;
    const float4 v = reinterpret_cast<const float4*>(y + (size_t)t * DD)[tid];
    float s  = v.x + v.y + v.z + v.w;
    float s2 = v.x*v.x + v.y*v.y + v.z*v.z + v.w*v.w;
    #pragma unroll
    for (int off = 32; off > 0; off >>= 1) {
        s  += __shfl_down(s,  off, 64);
        s2 += __shfl_down(s2, off, 64);
    }
    __shared__ float rs[4], rs2[4];
    const int wave = tid >> 6, lane = tid & 63;
    if (lane == 0) { rs[wave] = s; rs2[wave] = s2; }
    __syncthreads();
    s  = rs[0] + rs[1] + rs[2] + rs[3];
    s2 = rs2[0] + rs2[1] + rs2[2] + rs2[3];
    const float mu  = s * (1.f / DD);
    const float var = s2 * (1.f / DD) - mu * mu;
    const float inv = rsqrtf(var + 1e-5f);
    const float4 g = reinterpret_cast<const float4*>(gamma)[tid];
    const float4 b = reinterpret_cast<const float4*>(beta)[tid];
    float4 o;
    o.x = (v.x - mu) * inv * g.x + b.x;
    o.y = (v.y - mu) * inv * g.y + b.y;
    o.z = (v.z - mu) * inv * g.z + b.z;
    o.w = (v.w - mu) * inv * g.w + b.w;
    reinterpret_cast<float4*>(y + (size_t)t * DD)[tid] = o;
}

extern "C" void kernel_launch(void* const* d_in, const int* in_sizes, int n_in,
                              void* d_out, int out_size, void* d_ws, size_t ws_size,
                              hipStream_t stream) {
    const float* x     = (const float*)d_in[0];
    const float* c1    = (const float*)d_in[1];
    const float* c2    = (const float*)d_in[2];
    const float* gamma = (const float*)d_in[3];
    const float* beta  = (const float*)d_in[4];
    float* out = (float*)d_out;

    // compact workspace: peak ~88 MiB
    char* ws = (char*)d_ws;
    const size_t OFF_G     = 0;            // g bf16 [TT][HH] = 67,108,864
    const size_t OFF_B     = 67108864;     // B1p/B2p shared (sequential liveness)
    const size_t OFF_BIAS1 = 92274688;     // HH*4
    const size_t OFF_BIAS2 = 92291072;     // DD*4

    __bf16* gbuf  = (__bf16*)(ws + OFF_G);
    ushort* B1p   = (ushort*)(ws + OFF_B);
    ushort* B2p   = (ushort*)(ws + OFF_B);
    float*  bias1 = (float*) (ws + OFF_BIAS1);
    float*  bias2 = (float*) (ws + OFF_BIAS2);

    pack_b<DD><<<HH, 256, 0, stream>>>(c1, B1p, bias1);
    gemm_k<1><<<dim3(HH / 256, TT / 256), 512, 0, stream>>>(
        (const void*)x, (const __bf16*)B1p, bias1, gbuf, nullptr, nullptr);
    pack_b<HH><<<DD, 256, 0, stream>>>(c2, B2p, bias2);      // reuses B region after GEMM1
    gemm_k<2><<<dim3(DD / 128, TT / 256), 512, 0, stream>>>(
        (const void*)gbuf, (const __bf16*)B2p, bias2, nullptr, x, (float*)out);
    ln_k<<<TT, 256, 0, stream>>>(out, gamma, beta);
}

// Round 11
// 503.976 us; speedup vs baseline: 1.8798x; 1.1976x over previous
//
#include <hip/hip_runtime.h>
#include <hip/hip_bf16.h>
#include <math.h>

// Problem dims (fixed by the reference)
#define DD 1024
#define HH 4096
#define TT 8192

typedef __attribute__((ext_vector_type(4))) float f32x4;
typedef __attribute__((ext_vector_type(8))) __bf16 bf16x8;
typedef __attribute__((ext_vector_type(4))) __bf16 bf16x4;

__device__ __forceinline__ ushort f2bf(float f) {
    union { float f; unsigned u; } v; v.f = f;
    unsigned r = v.u + 0x7FFFu + ((v.u >> 16) & 1u);   // RNE
    return (ushort)(r >> 16);
}
__device__ __forceinline__ float clip1(float v){ return fminf(fmaxf(v, -1.f), 1.f); }
__device__ __forceinline__ float clip5(float v){ return fminf(fmaxf(v, -5.f), 5.f); }
__device__ __forceinline__ int frow(int r){ return (r >> 1) & 3; }   // 64B-row swizzle

__device__ __forceinline__ void gload_lds16(const void* g, void* l) {
    __builtin_amdgcn_global_load_lds((const __attribute__((address_space(1))) void*)g,
                                     (__attribute__((address_space(3))) void*)l, 16, 0, 0);
}

template<int N> __device__ __forceinline__ void vmwait() {
    if      constexpr (N == 0)  asm volatile("s_waitcnt vmcnt(0)" ::: "memory");
    else if constexpr (N == 1)  asm volatile("s_waitcnt vmcnt(1)" ::: "memory");
    else if constexpr (N == 2)  asm volatile("s_waitcnt vmcnt(2)" ::: "memory");
    else if constexpr (N == 3)  asm volatile("s_waitcnt vmcnt(3)" ::: "memory");
    else if constexpr (N == 4)  asm volatile("s_waitcnt vmcnt(4)" ::: "memory");
    else if constexpr (N == 6)  asm volatile("s_waitcnt vmcnt(6)" ::: "memory");
    else if constexpr (N == 8)  asm volatile("s_waitcnt vmcnt(8)" ::: "memory");
}

// ---- pack coeff [N,4,DIN] fp32 -> B^T bf16 [N][3*DIN] (clip); k=0 slice -> bias[N]
template<int DIN>
__global__ __launch_bounds__(256) void pack_b(const float* __restrict__ c,
                                              ushort* __restrict__ Bp,
                                              float* __restrict__ bias) {
    const int n = blockIdx.x;
    const float* src = c + (size_t)n * 4 * DIN;
    ushort* dst = Bp + (size_t)n * 3 * DIN;
    float bsum = 0.f;
    for (int d = threadIdx.x; d < DIN; d += 256) {
        bsum += clip1(src[d]);
        dst[d]         = f2bf(clip1(src[DIN + d]));
        dst[DIN + d]   = f2bf(clip1(src[2*DIN + d]));
        dst[2*DIN + d] = f2bf(clip1(src[3*DIN + d]));
    }
    #pragma unroll
    for (int off = 32; off > 0; off >>= 1) bsum += __shfl_down(bsum, off, 64);
    __shared__ float red[4];
    const int wave = threadIdx.x >> 6, lane = threadIdx.x & 63;
    if (lane == 0) red[wave] = bsum;
    __syncthreads();
    if (threadIdx.x == 0) bias[n] = red[0] + red[1] + red[2] + red[3];
}

// ---- x [T][D] fp32 -> A1 bf16 [T][3*D]: planes (v, v^2, v^3), v = clip5(x)
__global__ __launch_bounds__(256) void pack_a1(const float* __restrict__ x,
                                               __bf16* __restrict__ A1) {
    const int gid = blockIdx.x * 256 + threadIdx.x;   // 8 elems per thread
    const int t = gid >> 7, d0 = (gid & 127) * 8;
    const float* src = x + (size_t)t * DD + d0;
    const f32x4 a = *reinterpret_cast<const f32x4*>(src);
    const f32x4 b = *reinterpret_cast<const f32x4*>(src + 4);
    bf16x8 u0, u1, u2;
    #pragma unroll
    for (int j = 0; j < 4; ++j) {
        float v = clip5(a[j]); float v2 = v*v;
        u0[j] = (__bf16)v; u1[j] = (__bf16)v2; u2[j] = (__bf16)(v2*v);
        v = clip5(b[j]); v2 = v*v;
        u0[j+4] = (__bf16)v; u1[j+4] = (__bf16)v2; u2[j+4] = (__bf16)(v2*v);
    }
    __bf16* dst = A1 + (size_t)t * (3*DD) + d0;
    *reinterpret_cast<bf16x8*>(dst)          = u0;
    *reinterpret_cast<bf16x8*>(dst + DD)     = u1;
    *reinterpret_cast<bf16x8*>(dst + 2*DD)   = u2;
}

// ---- PURE bf16 GEMM1 256x256, BK=32, ring-4 lookahead-3, counted vmcnt(8),
// 1 barrier/iter, setprio, XCD swizzle. Both operands via pre-swizzled
// global_load_lds. Epilogue: *0.1+bias, clip5, gelu(erf), clip5 -> g bf16.
__global__ __launch_bounds__(512, 2) void gemm1_k(
    const __bf16* __restrict__ A, const __bf16* __restrict__ Bt,
    const float* __restrict__ bias, __bf16* __restrict__ gout)
{
    constexpr int K = 3*DD, NIT = K/32;
    constexpr int SLOT = 32768;                 // As 16KB @0, Bs 16KB @16384
    __shared__ char LB[4*SLOT];                 // 128KB ring-4

    const int tid = threadIdx.x, lane = tid & 63, wave = tid >> 6;
    const int wrow = wave >> 2, wcol = wave & 3;        // 2x4 waves, wave tile 128x64
    const int wg = blockIdx.x;                          // 512 wgs -> XCD swizzle
    const int wgid = (wg & 7) * 64 + (wg >> 3);         // bijective (512 % 8 == 0)
    const int m0 = (wgid & 31) * 256, n0 = (wgid >> 5) * 256;
    const int ln15 = lane & 15, l4 = lane >> 4;

    int aoff[8], boff[4];
    #pragma unroll
    for (int m = 0; m < 8; ++m) {
        const int r = wrow*128 + m*16 + ln15;
        aoff[m] = r*64 + ((l4 ^ frow(r)) << 4);
    }
    #pragma unroll
    for (int n = 0; n < 4; ++n) {
        const int r = wcol*64 + n*16 + ln15;
        boff[n] = 16384 + r*64 + ((l4 ^ frow(r)) << 4);
    }

    f32x4 acc[8][4];
    #pragma unroll
    for (int m = 0; m < 8; ++m)
        #pragma unroll
        for (int n = 0; n < 4; ++n)
            acc[m][n] = (f32x4){0.f, 0.f, 0.f, 0.f};

    auto issueL = [&](int i, int slot) {
        char* dst = LB + slot * SLOT;
        const int kc = 32*i;
        #pragma unroll
        for (int it = 0; it < 2; ++it) {
            const int c = it*512 + tid, row = c >> 2, ch = c & 3;
            gload_lds16(A  + (size_t)(m0 + row) * K + kc + ((ch ^ frow(row)) << 3),
                        dst + (size_t)c * 16);
        }
        #pragma unroll
        for (int it = 0; it < 2; ++it) {
            const int c = it*512 + tid, row = c >> 2, ch = c & 3;
            gload_lds16(Bt + (size_t)(n0 + row) * K + kc + ((ch ^ frow(row)) << 3),
                        dst + 16384 + (size_t)c * 16);
        }
    };

    issueL(0, 0); issueL(1, 1); issueL(2, 2);

    for (int i = 0; i < NIT; ++i) {
        if (i < NIT-2) vmwait<8>();            // own L(i) done; L(i+1),L(i+2) in flight
        else if (i == NIT-2) vmwait<4>();
        else vmwait<0>();
        __builtin_amdgcn_s_barrier();
        asm volatile("" ::: "memory");
        if (i + 3 < NIT) issueL(i+3, (i+3) & 3);
        const char* S = LB + (i & 3) * SLOT;
        bf16x8 af[8], bf[4];
        #pragma unroll
        for (int m = 0; m < 8; ++m) af[m] = *reinterpret_cast<const bf16x8*>(S + aoff[m]);
        #pragma unroll
        for (int n = 0; n < 4; ++n) bf[n] = *reinterpret_cast<const bf16x8*>(S + boff[n]);
        __builtin_amdgcn_s_setprio(1);
        #pragma unroll
        for (int m = 0; m < 8; ++m)
            #pragma unroll
            for (int n = 0; n < 4; ++n)
                acc[m][n] = __builtin_amdgcn_mfma_f32_16x16x32_bf16(af[m], bf[n], acc[m][n], 0, 0, 0);
        __builtin_amdgcn_s_setprio(0);
    }

    float bn[4];
    #pragma unroll
    for (int n = 0; n < 4; ++n) bn[n] = bias[n0 + wcol*64 + n*16 + ln15];
    #pragma unroll
    for (int m = 0; m < 8; ++m) {
        #pragma unroll
        for (int j = 0; j < 4; ++j) {
            const int gm = m0 + wrow*128 + m*16 + l4*4 + j;
            #pragma unroll
            for (int n = 0; n < 4; ++n) {
                const int gn = n0 + wcol*64 + n*16 + ln15;
                float v = clip5(0.1f * (acc[m][n][j] + bn[n]));
                float g = 0.5f * v * (1.f + erff(v * 0.70710678118654752f));
                g = clip5(g);
                gout[(size_t)gm * HH + gn] = (__bf16)g;
            }
        }
    }
}

// ---- R6-verbatim 256-row GEMM (PROVEN, 478us config): BK=32, 3 power phases,
// As v/v2/v3 planes double-buffered, B 3-slot ring, counted vmcnt.
template<int EPI>
__global__ __launch_bounds__(512, 2) void gemm_k(
    const void* __restrict__ Asrc, const __bf16* __restrict__ Bt,
    const float* __restrict__ bias,
    __bf16* __restrict__ gout,
    const float* __restrict__ resid, float* __restrict__ yout)
{
    constexpr int SD    = (EPI == 1) ? DD : HH;
    constexpr int K     = 3 * SD;
    constexpr int NIT   = SD / 32;
    constexpr int BN    = (EPI == 1) ? 256 : 128;
    constexpr int MF    = (EPI == 1) ? 8 : 4;
    constexpr int WN    = (EPI == 1) ? 4 : 2;
    constexpr int BCH   = (EPI == 1) ? 2 : 1;
    constexpr int BSLOT = BN * 64;
    constexpr int APL   = 16384;
    constexpr int ABUF  = 3 * APL;
    constexpr int VB    = (EPI == 1) ? 2 : 1;
    constexpr int VP1   = (EPI == 1) ? 6 : 3;

    __shared__ char LB[2*ABUF + 3*BSLOT];
    char* AsB = LB;
    char* BsB = LB + 2*ABUF;

    const int tid  = threadIdx.x;
    const int lane = tid & 63;
    const int wave = tid >> 6;
    const int wrow = wave / WN, wcol = wave % WN;
    const int m0 = blockIdx.y * 256, n0 = blockIdx.x * BN;
    const int ln15 = lane & 15, l4 = lane >> 4;

    int aoff[MF], boff[4];
    #pragma unroll
    for (int m = 0; m < MF; ++m) {
        const int r = wrow*(MF*16) + m*16 + ln15;
        aoff[m] = r*64 + ((l4 ^ frow(r)) << 4);
    }
    #pragma unroll
    for (int n = 0; n < 4; ++n) {
        const int r = wcol*64 + n*16 + ln15;
        boff[n] = r*64 + ((l4 ^ frow(r)) << 4);
    }

    f32x4 acc[MF][4];
    #pragma unroll
    for (int m = 0; m < MF; ++m)
        #pragma unroll
        for (int n = 0; n < 4; ++n)
            acc[m][n] = (f32x4){0.f, 0.f, 0.f, 0.f};

    auto issueB = [&](int kcol, int slot) {
        char* dst = BsB + slot * BSLOT;
        #pragma unroll
        for (int it = 0; it < BCH; ++it) {
            const int c = it*512 + tid, row = c >> 2, ch = c & 3;
            gload_lds16(Bt + (size_t)(n0 + row) * K + kcol + ((ch ^ frow(row)) << 3),
                        dst + (size_t)c * 16);
        }
    };

    f32x4  xw[4];
    bf16x8 gw[2];

    auto issueX = [&](int i) {
        if constexpr (EPI == 1) {
            const float* X = (const float*)Asrc;
            #pragma unroll
            for (int k = 0; k < 4; ++k) {
                const int c = k*512 + tid, row = c >> 3, ch = c & 7;
                xw[k] = *reinterpret_cast<const f32x4*>(
                    X + (size_t)(m0 + row) * DD + 32*i + ch*4);
            }
        } else {
            const __bf16* G = (const __bf16*)Asrc;
            #pragma unroll
            for (int k = 0; k < 2; ++k) {
                const int c = k*512 + tid, row = c >> 2, ch = c & 3;
                gw[k] = *reinterpret_cast<const bf16x8*>(
                    G + (size_t)(m0 + row) * HH + 32*i + ch*8);
            }
        }
    };

    auto powers = [&](char* Abuf) {
        if constexpr (EPI == 1) {
            #pragma unroll
            for (int k = 0; k < 4; ++k) {
                const int c = k*512 + tid, row = c >> 3, ch = c & 7, fr = frow(row);
                bf16x4 u0, u1, u2;
                #pragma unroll
                for (int j = 0; j < 4; ++j) {
                    const float v  = clip5(xw[k][j]);
                    const float v2 = v * v;
                    u0[j] = (__bf16)v; u1[j] = (__bf16)v2; u2[j] = (__bf16)(v2 * v);
                }
                const int base = row*64 + ((ch*8) ^ (fr << 4));
                *reinterpret_cast<bf16x4*>(Abuf +         base) = u0;
                *reinterpret_cast<bf16x4*>(Abuf +   APL + base) = u1;
                *reinterpret_cast<bf16x4*>(Abuf + 2*APL + base) = u2;
            }
        } else {
            #pragma unroll
            for (int k = 0; k < 2; ++k) {
                const int c = k*512 + tid, row = c >> 2, ch = c & 3, fr = frow(row);
                bf16x8 u1, u2;
                #pragma unroll
                for (int j = 0; j < 8; ++j) {
                    const float v  = (float)gw[k][j];
                    const float v2 = v * v;
                    u1[j] = (__bf16)v2; u2[j] = (__bf16)(v2 * v);
                }
                const int base = row*64 + ((ch << 4) ^ (fr << 4));
                *reinterpret_cast<bf16x8*>(Abuf +         base) = gw[k];
                *reinterpret_cast<bf16x8*>(Abuf +   APL + base) = u1;
                *reinterpret_cast<bf16x8*>(Abuf + 2*APL + base) = u2;
            }
        }
    };

    auto mfma_phase = [&](const char* Abuf, int p, int s) {
        const char* As_ = Abuf + p * APL;
        const char* Bs_ = BsB + s * BSLOT;
        bf16x8 af[MF], bf[4];
        #pragma unroll
        for (int m = 0; m < MF; ++m) af[m] = *reinterpret_cast<const bf16x8*>(As_ + aoff[m]);
        #pragma unroll
        for (int n = 0; n < 4; ++n) bf[n] = *reinterpret_cast<const bf16x8*>(Bs_ + boff[n]);
        __builtin_amdgcn_s_setprio(1);
        #pragma unroll
        for (int m = 0; m < MF; ++m)
            #pragma unroll
            for (int n = 0; n < 4; ++n)
                acc[m][n] = __builtin_amdgcn_mfma_f32_16x16x32_bf16(af[m], bf[n], acc[m][n], 0, 0, 0);
        __builtin_amdgcn_s_setprio(0);
    };

    issueX(0);
    issueB(0, 0);
    issueB(SD, 1);
    powers(AsB);
    asm volatile("s_waitcnt lgkmcnt(0)" ::: "memory");

    for (int i = 0; i < NIT; ++i) {
        const bool nl = (i + 1 < NIT);
        char* cur = AsB + (i & 1) * ABUF;
        char* nxt = AsB + ((i + 1) & 1) * ABUF;
        const int d0 = 32*i, d1 = d0 + 32;
        vmwait<VB>();
        __builtin_amdgcn_s_barrier();
        asm volatile("" ::: "memory");
        if (nl) issueX(i+1);
        issueB(2*SD + d0, 2);
        mfma_phase(cur, 0, 0);
        if (nl) vmwait<VP1>(); else vmwait<VB>();
        __builtin_amdgcn_s_barrier();
        asm volatile("" ::: "memory");
        if (nl) issueB(d1, 0);
        mfma_phase(cur, 1, 1);
        if (nl) vmwait<VB>(); else vmwait<0>();
        __builtin_amdgcn_s_barrier();
        asm volatile("" ::: "memory");
        if (nl) issueB(SD + d1, 1);
        mfma_phase(cur, 2, 2);
        if (nl) {
            powers(nxt);
            asm volatile("s_waitcnt lgkmcnt(0)" ::: "memory");
        }
    }

    float bn[4];
    #pragma unroll
    for (int n = 0; n < 4; ++n) bn[n] = bias[n0 + wcol*64 + n*16 + ln15];

    #pragma unroll
    for (int m = 0; m < MF; ++m) {
        #pragma unroll
        for (int j = 0; j < 4; ++j) {
            const int gm = m0 + wrow*(MF*16) + m*16 + l4*4 + j;
            #pragma unroll
            for (int n = 0; n < 4; ++n) {
                const int gn = n0 + wcol*64 + n*16 + ln15;
                float v = 0.1f * (acc[m][n][j] + bn[n]);
                v = clip5(v);
                if (EPI == 1) {
                    float g = 0.5f * v * (1.f + erff(v * 0.70710678118654752f));
                    g = clip5(g);
                    gout[(size_t)gm * HH + gn] = (__bf16)g;
                } else {
                    yout[(size_t)gm * DD + gn] = v + resid[(size_t)gm * DD + gn];
                }
            }
        }
    }
}

// ---- row LayerNorm over D=1024, in-place, one block per row
__global__ __launch_bounds__(256) void ln_k(float* y,
                                            const float* __restrict__ gamma,
                                            const float* __restrict__ beta) {
    const int t = blockIdx.x, tid = threadIdx.x;
    const float4 v = reinterpret_cast<const float4*>(y + (size_t)t * DD)[tid];
    float s  = v.x + v.y + v.z + v.w;
    float s2 = v.x*v.x + v.y*v.y + v.z*v.z + v.w*v.w;
    #pragma unroll
    for (int off = 32; off > 0; off >>= 1) {
        s  += __shfl_down(s,  off, 64);
        s2 += __shfl_down(s2, off, 64);
    }
    __shared__ float rs[4], rs2[4];
    const int wave = tid >> 6, lane = tid & 63;
    if (lane == 0) { rs[wave] = s; rs2[wave] = s2; }
    __syncthreads();
    s  = rs[0] + rs[1] + rs[2] + rs[3];
    s2 = rs2[0] + rs2[1] + rs2[2] + rs2[3];
    const float mu  = s * (1.f / DD);
    const float var = s2 * (1.f / DD) - mu * mu;
    const float inv = rsqrtf(var + 1e-5f);
    const float4 g = reinterpret_cast<const float4*>(gamma)[tid];
    const float4 b = reinterpret_cast<const float4*>(beta)[tid];
    float4 o;
    o.x = (v.x - mu) * inv * g.x + b.x;
    o.y = (v.y - mu) * inv * g.y + b.y;
    o.z = (v.z - mu) * inv * g.z + b.z;
    o.w = (v.w - mu) * inv * g.w + b.w;
    reinterpret_cast<float4*>(y + (size_t)t * DD)[tid] = o;
}

extern "C" void kernel_launch(void* const* d_in, const int* in_sizes, int n_in,
                              void* d_out, int out_size, void* d_ws, size_t ws_size,
                              hipStream_t stream) {
    const float* x     = (const float*)d_in[0];
    const float* c1    = (const float*)d_in[1];
    const float* c2    = (const float*)d_in[2];
    const float* gamma = (const float*)d_in[3];
    const float* beta  = (const float*)d_in[4];
    float* out = (float*)d_out;
    char* ws = (char*)d_ws;

    // FAST path needs 142,626,816 B: A1(50,331,648) + g(67,108,864) +
    // B-shared(25,165,824) + bias1(16,384) + bias2(4,096). No d_out scratch.
    if (ws_size >= (size_t)142626816) {
        __bf16* A1    = (__bf16*)(ws + 0);
        __bf16* gbuf  = (__bf16*)(ws + 50331648);
        ushort* B1p   = (ushort*)(ws + 117440512);
        ushort* B2p   = (ushort*)(ws + 117440512);     // sequential liveness
        float*  bias1 = (float*) (ws + 142606336);
        float*  bias2 = (float*) (ws + 142622720);

        pack_b<DD><<<HH, 256, 0, stream>>>(c1, B1p, bias1);
        pack_a1<<<(TT * DD) / (256 * 8), 256, 0, stream>>>(x, A1);
        gemm1_k<<<512, 512, 0, stream>>>(A1, (const __bf16*)B1p, bias1, gbuf);
        pack_b<HH><<<DD, 256, 0, stream>>>(c2, B2p, bias2);    // B1 dead now
        gemm_k<2><<<dim3(DD / 128, TT / 256), 512, 0, stream>>>(
            (const void*)gbuf, (const __bf16*)B2p, bias2, nullptr, x, (float*)out);
        ln_k<<<TT, 256, 0, stream>>>(out, gamma, beta);
    } else {
        // SAFE path: R6-verbatim, proven 92,295,168-byte layout (478us).
        __bf16* gbuf  = (__bf16*)(ws + 0);
        ushort* B1p   = (ushort*)(ws + 67108864);
        ushort* B2p   = (ushort*)(ws + 67108864);
        float*  bias1 = (float*) (ws + 92274688);
        float*  bias2 = (float*) (ws + 92291072);

        pack_b<DD><<<HH, 256, 0, stream>>>(c1, B1p, bias1);
        gemm_k<1><<<dim3(HH / 256, TT / 256), 512, 0, stream>>>(
            (const void*)x, (const __bf16*)B1p, bias1, gbuf, nullptr, nullptr);
        pack_b<HH><<<DD, 256, 0, stream>>>(c2, B2p, bias2);
        gemm_k<2><<<dim3(DD / 128, TT / 256), 512, 0, stream>>>(
            (const void*)gbuf, (const __bf16*)B2p, bias2, nullptr, x, (float*)out);
        ln_k<<<TT, 256, 0, stream>>>(out, gamma, beta);
    }
}

// Round 12
// 488.314 us; speedup vs baseline: 1.9401x; 1.0321x over previous
//
#include <hip/hip_runtime.h>
#include <hip/hip_bf16.h>
#include <math.h>

// Problem dims (fixed by the reference)
#define DD 1024
#define HH 4096
#define TT 8192

typedef __attribute__((ext_vector_type(4))) float f32x4;
typedef __attribute__((ext_vector_type(8))) __bf16 bf16x8;
typedef __attribute__((ext_vector_type(4))) __bf16 bf16x4;

__device__ __forceinline__ ushort f2bf(float f) {
    union { float f; unsigned u; } v; v.f = f;
    unsigned r = v.u + 0x7FFFu + ((v.u >> 16) & 1u);   // RNE
    return (ushort)(r >> 16);
}
__device__ __forceinline__ float clip1(float v){ return fminf(fmaxf(v, -1.f), 1.f); }
__device__ __forceinline__ float clip5(float v){ return fminf(fmaxf(v, -5.f), 5.f); }
__device__ __forceinline__ int frow(int r){ return (r >> 1) & 3; }   // 64B-row swizzle

__device__ __forceinline__ void gload_lds16(const void* g, void* l) {
    __builtin_amdgcn_global_load_lds((const __attribute__((address_space(1))) void*)g,
                                     (__attribute__((address_space(3))) void*)l, 16, 0, 0);
}

template<int N> __device__ __forceinline__ void vmwait() {
    if      constexpr (N == 0)  asm volatile("s_waitcnt vmcnt(0)" ::: "memory");
    else if constexpr (N == 1)  asm volatile("s_waitcnt vmcnt(1)" ::: "memory");
    else if constexpr (N == 3)  asm volatile("s_waitcnt vmcnt(3)" ::: "memory");
    else if constexpr (N == 4)  asm volatile("s_waitcnt vmcnt(4)" ::: "memory");
    else if constexpr (N == 8)  asm volatile("s_waitcnt vmcnt(8)" ::: "memory");
}

// ---- pack coeff [N,4,DIN] fp32 -> B^T bf16 [N][3*DIN] (clip); k=0 slice -> bias[N]
template<int DIN>
__global__ __launch_bounds__(256) void pack_b(const float* __restrict__ c,
                                              ushort* __restrict__ Bp,
                                              float* __restrict__ bias) {
    const int n = blockIdx.x;
    const float* src = c + (size_t)n * 4 * DIN;
    ushort* dst = Bp + (size_t)n * 3 * DIN;
    float bsum = 0.f;
    for (int d = threadIdx.x; d < DIN; d += 256) {
        bsum += clip1(src[d]);
        dst[d]         = f2bf(clip1(src[DIN + d]));
        dst[DIN + d]   = f2bf(clip1(src[2*DIN + d]));
        dst[2*DIN + d] = f2bf(clip1(src[3*DIN + d]));
    }
    #pragma unroll
    for (int off = 32; off > 0; off >>= 1) bsum += __shfl_down(bsum, off, 64);
    __shared__ float red[4];
    const int wave = threadIdx.x >> 6, lane = threadIdx.x & 63;
    if (lane == 0) red[wave] = bsum;
    __syncthreads();
    if (threadIdx.x == 0) bias[n] = red[0] + red[1] + red[2] + red[3];
}

// ---- x [T][D] fp32 -> A1 bf16 [T][3*D]: planes (v, v^2, v^3), v = clip5(x)
__global__ __launch_bounds__(256) void pack_a1(const float* __restrict__ x,
                                               __bf16* __restrict__ A1) {
    const int gid = blockIdx.x * 256 + threadIdx.x;   // 8 elems per thread
    const int t = gid >> 7, d0 = (gid & 127) * 8;
    const float* src = x + (size_t)t * DD + d0;
    const f32x4 a = *reinterpret_cast<const f32x4*>(src);
    const f32x4 b = *reinterpret_cast<const f32x4*>(src + 4);
    bf16x8 u0, u1, u2;
    #pragma unroll
    for (int j = 0; j < 4; ++j) {
        float v = clip5(a[j]); float v2 = v*v;
        u0[j] = (__bf16)v; u1[j] = (__bf16)v2; u2[j] = (__bf16)(v2*v);
        v = clip5(b[j]); v2 = v*v;
        u0[j+4] = (__bf16)v; u1[j+4] = (__bf16)v2; u2[j+4] = (__bf16)(v2*v);
    }
    __bf16* dst = A1 + (size_t)t * (3*DD) + d0;
    *reinterpret_cast<bf16x8*>(dst)          = u0;
    *reinterpret_cast<bf16x8*>(dst + DD)     = u1;
    *reinterpret_cast<bf16x8*>(dst + 2*DD)   = u2;
}

// ---- PURE bf16 GEMM1 256x256, BK=32, ring-4 lookahead-3, counted vmcnt(8),
// 1 barrier/iter, setprio. XCD 2D super-tile swizzle: XCD c owns an 8m x 8n
// panel group (A fetch/XCD 12MB, B 12MB — was 50MB A with the 1D swizzle).
// Epilogue: *0.1+bias, clip5, gelu(erf), clip5 -> g bf16.
__global__ __launch_bounds__(512, 2) void gemm1_k(
    const __bf16* __restrict__ A, const __bf16* __restrict__ Bt,
    const float* __restrict__ bias, __bf16* __restrict__ gout)
{
    constexpr int K = 3*DD, NIT = K/32;
    constexpr int SLOT = 32768;                 // As 16KB @0, Bs 16KB @16384
    __shared__ char LB[4*SLOT];                 // 128KB ring-4

    const int tid = threadIdx.x, lane = tid & 63, wave = tid >> 6;
    const int wrow = wave >> 2, wcol = wave & 3;        // 2x4 waves, wave tile 128x64
    // 512 blocks; dispatch XCD = b%8. XCD c -> super-tile (c&3 of 4 m-groups,
    // c>>2 of 2 n-groups), q enumerates 8x8 panels inside.
    const int b = blockIdx.x, cx = b & 7, q = b >> 3;   // q in 0..63
    const int m0 = (((cx & 3) << 3) + (q & 7)) * 256;   // 32 m-panels
    const int n0 = (((cx >> 2) << 3) + (q >> 3)) * 256; // 16 n-panels
    const int ln15 = lane & 15, l4 = lane >> 4;

    int aoff[8], boff[4];
    #pragma unroll
    for (int m = 0; m < 8; ++m) {
        const int r = wrow*128 + m*16 + ln15;
        aoff[m] = r*64 + ((l4 ^ frow(r)) << 4);
    }
    #pragma unroll
    for (int n = 0; n < 4; ++n) {
        const int r = wcol*64 + n*16 + ln15;
        boff[n] = 16384 + r*64 + ((l4 ^ frow(r)) << 4);
    }

    f32x4 acc[8][4];
    #pragma unroll
    for (int m = 0; m < 8; ++m)
        #pragma unroll
        for (int n = 0; n < 4; ++n)
            acc[m][n] = (f32x4){0.f, 0.f, 0.f, 0.f};

    auto issueL = [&](int i, int slot) {
        char* dst = LB + slot * SLOT;
        const int kc = 32*i;
        #pragma unroll
        for (int it = 0; it < 2; ++it) {
            const int c = it*512 + tid, row = c >> 2, ch = c & 3;
            gload_lds16(A  + (size_t)(m0 + row) * K + kc + ((ch ^ frow(row)) << 3),
                        dst + (size_t)c * 16);
        }
        #pragma unroll
        for (int it = 0; it < 2; ++it) {
            const int c = it*512 + tid, row = c >> 2, ch = c & 3;
            gload_lds16(Bt + (size_t)(n0 + row) * K + kc + ((ch ^ frow(row)) << 3),
                        dst + 16384 + (size_t)c * 16);
        }
    };

    issueL(0, 0); issueL(1, 1); issueL(2, 2);

    for (int i = 0; i < NIT; ++i) {
        if (i < NIT-2) vmwait<8>();            // own L(i) done; L(i+1),L(i+2) in flight
        else if (i == NIT-2) vmwait<4>();
        else vmwait<0>();
        __builtin_amdgcn_s_barrier();
        asm volatile("" ::: "memory");
        if (i + 3 < NIT) issueL(i+3, (i+3) & 3);
        const char* S = LB + (i & 3) * SLOT;
        bf16x8 af[8], bf[4];
        #pragma unroll
        for (int m = 0; m < 8; ++m) af[m] = *reinterpret_cast<const bf16x8*>(S + aoff[m]);
        #pragma unroll
        for (int n = 0; n < 4; ++n) bf[n] = *reinterpret_cast<const bf16x8*>(S + boff[n]);
        __builtin_amdgcn_s_setprio(1);
        #pragma unroll
        for (int m = 0; m < 8; ++m)
            #pragma unroll
            for (int n = 0; n < 4; ++n)
                acc[m][n] = __builtin_amdgcn_mfma_f32_16x16x32_bf16(af[m], bf[n], acc[m][n], 0, 0, 0);
        __builtin_amdgcn_s_setprio(0);
    }

    float bn[4];
    #pragma unroll
    for (int n = 0; n < 4; ++n) bn[n] = bias[n0 + wcol*64 + n*16 + ln15];
    #pragma unroll
    for (int m = 0; m < 8; ++m) {
        #pragma unroll
        for (int j = 0; j < 4; ++j) {
            const int gm = m0 + wrow*128 + m*16 + l4*4 + j;
            #pragma unroll
            for (int n = 0; n < 4; ++n) {
                const int gn = n0 + wcol*64 + n*16 + ln15;
                float v = clip5(0.1f * (acc[m][n][j] + bn[n]));
                float g = 0.5f * v * (1.f + erff(v * 0.70710678118654752f));
                g = clip5(g);
                gout[(size_t)gm * HH + gn] = (__bf16)g;
            }
        }
    }
}

// ---- GEMM2 (R6/R11-proven body, indexing-only change): 256x128, BK=32,
// 3 power phases per iter, As v/v2/v3 planes double-buffered, B 3-slot ring,
// counted vmcnt. XCD super-tile swizzle: XCD c owns 8m x 4n panels
// (g fetch/XCD 16MB, B2 12MB — was 64MB g with x-major dispatch).
__global__ __launch_bounds__(512, 2) void gemm2_k(
    const __bf16* __restrict__ G, const __bf16* __restrict__ Bt,
    const float* __restrict__ bias,
    const float* __restrict__ resid, float* __restrict__ yout)
{
    constexpr int SD    = HH;
    constexpr int K     = 3 * SD;
    constexpr int NIT   = SD / 32;
    constexpr int BN    = 128;
    constexpr int MF    = 4, WN = 2;
    constexpr int BSLOT = BN * 64;
    constexpr int APL   = 16384;
    constexpr int ABUF  = 3 * APL;
    constexpr int VB    = 1, VP1 = 3;

    __shared__ char LB[2*ABUF + 3*BSLOT];         // 120KB
    char* AsB = LB;
    char* BsB = LB + 2*ABUF;

    const int tid  = threadIdx.x;
    const int lane = tid & 63;
    const int wave = tid >> 6;
    const int wrow = wave / WN, wcol = wave % WN;
    // 256 blocks; XCD c = b%8 owns (c&3)-th of 4 m-groups x (c>>2)-th of 2 n-groups
    const int b = blockIdx.x, cx = b & 7, q = b >> 3;   // q in 0..31
    const int m0 = (((cx & 3) << 3) + (q & 7)) * 256;   // 32 m-panels
    const int n0 = (((cx >> 2) << 2) + (q >> 3)) * BN;  // 8 n-panels
    const int ln15 = lane & 15, l4 = lane >> 4;

    int aoff[MF], boff[4];
    #pragma unroll
    for (int m = 0; m < MF; ++m) {
        const int r = wrow*(MF*16) + m*16 + ln15;
        aoff[m] = r*64 + ((l4 ^ frow(r)) << 4);
    }
    #pragma unroll
    for (int n = 0; n < 4; ++n) {
        const int r = wcol*64 + n*16 + ln15;
        boff[n] = r*64 + ((l4 ^ frow(r)) << 4);
    }

    f32x4 acc[MF][4];
    #pragma unroll
    for (int m = 0; m < MF; ++m)
        #pragma unroll
        for (int n = 0; n < 4; ++n)
            acc[m][n] = (f32x4){0.f, 0.f, 0.f, 0.f};

    auto issueB = [&](int kcol, int slot) {
        char* dst = BsB + slot * BSLOT;
        const int c = tid, row = c >> 2, ch = c & 3;
        gload_lds16(Bt + (size_t)(n0 + row) * K + kcol + ((ch ^ frow(row)) << 3),
                    dst + (size_t)c * 16);
    };

    bf16x8 gw[2];

    auto issueX = [&](int i) {
        #pragma unroll
        for (int k = 0; k < 2; ++k) {
            const int c = k*512 + tid, row = c >> 2, ch = c & 3;
            gw[k] = *reinterpret_cast<const bf16x8*>(
                G + (size_t)(m0 + row) * HH + 32*i + ch*8);
        }
    };

    auto powers = [&](char* Abuf) {
        #pragma unroll
        for (int k = 0; k < 2; ++k) {
            const int c = k*512 + tid, row = c >> 2, ch = c & 3, fr = frow(row);
            bf16x8 u1, u2;
            #pragma unroll
            for (int j = 0; j < 8; ++j) {
                const float v  = (float)gw[k][j];
                const float v2 = v * v;
                u1[j] = (__bf16)v2; u2[j] = (__bf16)(v2 * v);
            }
            const int base = row*64 + ((ch << 4) ^ (fr << 4));
            *reinterpret_cast<bf16x8*>(Abuf +         base) = gw[k];
            *reinterpret_cast<bf16x8*>(Abuf +   APL + base) = u1;
            *reinterpret_cast<bf16x8*>(Abuf + 2*APL + base) = u2;
        }
    };

    auto mfma_phase = [&](const char* Abuf, int p, int s) {
        const char* As_ = Abuf + p * APL;
        const char* Bs_ = BsB + s * BSLOT;
        bf16x8 af[MF], bf[4];
        #pragma unroll
        for (int m = 0; m < MF; ++m) af[m] = *reinterpret_cast<const bf16x8*>(As_ + aoff[m]);
        #pragma unroll
        for (int n = 0; n < 4; ++n) bf[n] = *reinterpret_cast<const bf16x8*>(Bs_ + boff[n]);
        __builtin_amdgcn_s_setprio(1);
        #pragma unroll
        for (int m = 0; m < MF; ++m)
            #pragma unroll
            for (int n = 0; n < 4; ++n)
                acc[m][n] = __builtin_amdgcn_mfma_f32_16x16x32_bf16(af[m], bf[n], acc[m][n], 0, 0, 0);
        __builtin_amdgcn_s_setprio(0);
    };

    issueX(0);
    issueB(0, 0);
    issueB(SD, 1);
    powers(AsB);
    asm volatile("s_waitcnt lgkmcnt(0)" ::: "memory");

    for (int i = 0; i < NIT; ++i) {
        const bool nl = (i + 1 < NIT);
        char* cur = AsB + (i & 1) * ABUF;
        char* nxt = AsB + ((i + 1) & 1) * ABUF;
        const int d0 = 32*i, d1 = d0 + 32;
        vmwait<VB>();
        __builtin_amdgcn_s_barrier();
        asm volatile("" ::: "memory");
        if (nl) issueX(i+1);
        issueB(2*SD + d0, 2);
        mfma_phase(cur, 0, 0);
        if (nl) vmwait<VP1>(); else vmwait<VB>();
        __builtin_amdgcn_s_barrier();
        asm volatile("" ::: "memory");
        if (nl) issueB(d1, 0);
        mfma_phase(cur, 1, 1);
        if (nl) vmwait<VB>(); else vmwait<0>();
        __builtin_amdgcn_s_barrier();
        asm volatile("" ::: "memory");
        if (nl) issueB(SD + d1, 1);
        mfma_phase(cur, 2, 2);
        if (nl) {
            powers(nxt);
            asm volatile("s_waitcnt lgkmcnt(0)" ::: "memory");
        }
    }

    float bn[4];
    #pragma unroll
    for (int n = 0; n < 4; ++n) bn[n] = bias[n0 + wcol*64 + n*16 + ln15];

    #pragma unroll
    for (int m = 0; m < MF; ++m) {
        #pragma unroll
        for (int j = 0; j < 4; ++j) {
            const int gm = m0 + wrow*(MF*16) + m*16 + l4*4 + j;
            #pragma unroll
            for (int n = 0; n < 4; ++n) {
                const int gn = n0 + wcol*64 + n*16 + ln15;
                float v = 0.1f * (acc[m][n][j] + bn[n]);
                v = clip5(v);
                yout[(size_t)gm * DD + gn] = v + resid[(size_t)gm * DD + gn];
            }
        }
    }
}

// ---- row LayerNorm over D=1024, in-place, one block per row
__global__ __launch_bounds__(256) void ln_k(float* y,
                                            const float* __restrict__ gamma,
                                            const float* __restrict__ beta) {
    const int t = blockIdx.x, tid = threadIdx.x;
    const float4 v = reinterpret_cast<const float4*>(y + (size_t)t * DD)[tid];
    float s  = v.x + v.y + v.z + v.w;
    float s2 = v.x*v.x + v.y*v.y + v.z*v.z + v.w*v.w;
    #pragma unroll
    for (int off = 32; off > 0; off >>= 1) {
        s  += __shfl_down(s,  off, 64);
        s2 += __shfl_down(s2, off, 64);
    }
    __shared__ float rs[4], rs2[4];
    const int wave = tid >> 6, lane = tid & 63;
    if (lane == 0) { rs[wave] = s; rs2[wave] = s2; }
    __syncthreads();
    s  = rs[0] + rs[1] + rs[2] + rs[3];
    s2 = rs2[0] + rs2[1] + rs2[2] + rs2[3];
    const float mu  = s * (1.f / DD);
    const float var = s2 * (1.f / DD) - mu * mu;
    const float inv = rsqrtf(var + 1e-5f);
    const float4 g = reinterpret_cast<const float4*>(gamma)[tid];
    const float4 b = reinterpret_cast<const float4*>(beta)[tid];
    float4 o;
    o.x = (v.x - mu) * inv * g.x + b.x;
    o.y = (v.y - mu) * inv * g.y + b.y;
    o.z = (v.z - mu) * inv * g.z + b.z;
    o.w = (v.w - mu) * inv * g.w + b.w;
    reinterpret_cast<float4*>(y + (size_t)t * DD)[tid] = o;
}

extern "C" void kernel_launch(void* const* d_in, const int* in_sizes, int n_in,
                              void* d_out, int out_size, void* d_ws, size_t ws_size,
                              hipStream_t stream) {
    const float* x     = (const float*)d_in[0];
    const float* c1    = (const float*)d_in[1];
    const float* c2    = (const float*)d_in[2];
    const float* gamma = (const float*)d_in[3];
    const float* beta  = (const float*)d_in[4];
    float* out = (float*)d_out;
    char* ws = (char*)d_ws;

    // Proven-fitting layout (R11 fast path ran): 142,626,816 B total.
    __bf16* A1    = (__bf16*)(ws + 0);             // [TT][3*DD] bf16 = 50,331,648
    __bf16* gbuf  = (__bf16*)(ws + 50331648);      // [TT][HH]   bf16 = 67,108,864
    ushort* B1p   = (ushort*)(ws + 117440512);     // B1/B2 shared, sequential liveness
    ushort* B2p   = (ushort*)(ws + 117440512);
    float*  bias1 = (float*) (ws + 142606336);
    float*  bias2 = (float*) (ws + 142622720);

    pack_b<DD><<<HH, 256, 0, stream>>>(c1, B1p, bias1);
    pack_a1<<<(TT * DD) / (256 * 8), 256, 0, stream>>>(x, A1);
    gemm1_k<<<512, 512, 0, stream>>>(A1, (const __bf16*)B1p, bias1, gbuf);
    pack_b<HH><<<DD, 256, 0, stream>>>(c2, B2p, bias2);    // B1 dead now
    gemm2_k<<<256, 512, 0, stream>>>(gbuf, (const __bf16*)B2p, bias2, x, (float*)out);
    ln_k<<<TT, 256, 0, stream>>>(out, gamma, beta);
}

// Round 13
// 480.858 us; speedup vs baseline: 1.9702x; 1.0155x over previous
//
#include <hip/hip_runtime.h>
#include <hip/hip_bf16.h>
#include <math.h>

// Problem dims (fixed by the reference)
#define DD 1024
#define HH 4096
#define TT 8192

typedef __attribute__((ext_vector_type(4))) float f32x4;
typedef __attribute__((ext_vector_type(8))) __bf16 bf16x8;

__device__ __forceinline__ ushort f2bf(float f) {
    union { float f; unsigned u; } v; v.f = f;
    unsigned r = v.u + 0x7FFFu + ((v.u >> 16) & 1u);   // RNE
    return (ushort)(r >> 16);
}
__device__ __forceinline__ float clip1(float v){ return fminf(fmaxf(v, -1.f), 1.f); }
__device__ __forceinline__ float clip5(float v){ return fminf(fmaxf(v, -5.f), 5.f); }
__device__ __forceinline__ int frow(int r){ return (r >> 1) & 3; }               // 64B rows
__device__ __forceinline__ int fr3(int r){ return ((r >> 1) ^ (r >> 3)) & 7; }   // 128B rows

__device__ __forceinline__ void gload_lds16(const void* g, void* l) {
    __builtin_amdgcn_global_load_lds((const __attribute__((address_space(1))) void*)g,
                                     (__attribute__((address_space(3))) void*)l, 16, 0, 0);
}

template<int N> __device__ __forceinline__ void vmwait() {
    if      constexpr (N == 0)  asm volatile("s_waitcnt vmcnt(0)" ::: "memory");
    else if constexpr (N == 3)  asm volatile("s_waitcnt vmcnt(3)" ::: "memory");
}

// ---- pack coeff [N,4,DIN] fp32 -> B^T bf16 [N][3*DIN] (clip); k=0 slice -> bias[N]
template<int DIN>
__global__ __launch_bounds__(256) void pack_b(const float* __restrict__ c,
                                              ushort* __restrict__ Bp,
                                              float* __restrict__ bias) {
    const int n = blockIdx.x;
    const float* src = c + (size_t)n * 4 * DIN;
    ushort* dst = Bp + (size_t)n * 3 * DIN;
    float bsum = 0.f;
    for (int d = threadIdx.x; d < DIN; d += 256) {
        bsum += clip1(src[d]);
        dst[d]         = f2bf(clip1(src[DIN + d]));
        dst[DIN + d]   = f2bf(clip1(src[2*DIN + d]));
        dst[2*DIN + d] = f2bf(clip1(src[3*DIN + d]));
    }
    #pragma unroll
    for (int off = 32; off > 0; off >>= 1) bsum += __shfl_down(bsum, off, 64);
    __shared__ float red[4];
    const int wave = threadIdx.x >> 6, lane = threadIdx.x & 63;
    if (lane == 0) red[wave] = bsum;
    __syncthreads();
    if (threadIdx.x == 0) bias[n] = red[0] + red[1] + red[2] + red[3];
}

// ---- x [T][D] fp32 -> A1 bf16 [T][3*D]: planes (v, v^2, v^3), v = clip5(x)
__global__ __launch_bounds__(256) void pack_a1(const float* __restrict__ x,
                                               __bf16* __restrict__ A1) {
    const int gid = blockIdx.x * 256 + threadIdx.x;   // 8 elems per thread
    const int t = gid >> 7, d0 = (gid & 127) * 8;
    const float* src = x + (size_t)t * DD + d0;
    const f32x4 a = *reinterpret_cast<const f32x4*>(src);
    const f32x4 b = *reinterpret_cast<const f32x4*>(src + 4);
    bf16x8 u0, u1, u2;
    #pragma unroll
    for (int j = 0; j < 4; ++j) {
        float v = clip5(a[j]); float v2 = v*v;
        u0[j] = (__bf16)v; u1[j] = (__bf16)v2; u2[j] = (__bf16)(v2*v);
        v = clip5(b[j]); v2 = v*v;
        u0[j+4] = (__bf16)v; u1[j+4] = (__bf16)v2; u2[j+4] = (__bf16)(v2*v);
    }
    __bf16* dst = A1 + (size_t)t * (3*DD) + d0;
    *reinterpret_cast<bf16x8*>(dst)          = u0;
    *reinterpret_cast<bf16x8*>(dst + DD)     = u1;
    *reinterpret_cast<bf16x8*>(dst + 2*DD)   = u2;
}

// ---- GEMM1 v3: pure bf16 256x256, BK=64, ring-2 full tiles, 4 quadrant
// sub-phases/tile with interleaved staging, ONE vmcnt(0)+barrier per tile
// (48 barriers total). fr3 swizzle on 128B rows; XCD 2D super-tile swizzle.
// Epilogue: *0.1+bias, clip5, gelu(erf), clip5 -> g bf16 [T][H].
__global__ __launch_bounds__(512, 2) void gemm1_k(
    const __bf16* __restrict__ A, const __bf16* __restrict__ Bt,
    const float* __restrict__ bias, __bf16* __restrict__ gout)
{
    constexpr int K = 3*DD, NT = K/64;          // 48 K-tiles
    __shared__ char LB[131072];                  // A: 2x32KB @0; B: 2x32KB @65536

    const int tid = threadIdx.x, lane = tid & 63, wave = tid >> 6;
    const int wrow = wave >> 2, wcol = wave & 3;        // 2x4 waves, wave tile 128x64
    const int b = blockIdx.x, cx = b & 7, q = b >> 3;   // XCD c owns 8m x 8n panels
    const int m0 = (((cx & 3) << 3) + (q & 7)) * 256;
    const int n0 = (((cx >> 2) << 3) + (q >> 3)) * 256;
    const int ln15 = lane & 15, l4 = lane >> 4;

    // frag byte offsets within a [256][64] bf16 tile (128B rows, fr3 swizzle);
    // kc=1 chunk = kc=0 chunk XOR bit2 -> byte XOR 64.
    int aoff[8], boff[4];
    #pragma unroll
    for (int m = 0; m < 8; ++m) {
        const int r = wrow*128 + m*16 + ln15;
        aoff[m] = r*128 + ((l4 ^ fr3(r)) << 4);
    }
    #pragma unroll
    for (int n = 0; n < 4; ++n) {
        const int r = wcol*64 + n*16 + ln15;
        boff[n] = r*128 + ((l4 ^ fr3(r)) << 4);
    }

    f32x4 acc[8][4];
    #pragma unroll
    for (int m = 0; m < 8; ++m)
        #pragma unroll
        for (int n = 0; n < 4; ++n)
            acc[m][n] = (f32x4){0.f, 0.f, 0.f, 0.f};

    // stage rounds r0,r0+1 (of 4) of tile t: 512thr x 16B x 2 = 16KB
    auto stageA = [&](int t, int r0) {
        char* dst = LB + (t & 1) * 32768;
        #pragma unroll
        for (int it = 0; it < 2; ++it) {
            const int c = (r0 + it)*512 + tid, row = c >> 3, ch = c & 7;
            gload_lds16(A + (size_t)(m0 + row) * K + t*64 + ((ch ^ fr3(row)) << 3),
                        dst + (size_t)c * 16);
        }
    };
    auto stageB = [&](int t, int r0) {
        char* dst = LB + 65536 + (t & 1) * 32768;
        #pragma unroll
        for (int it = 0; it < 2; ++it) {
            const int c = (r0 + it)*512 + tid, row = c >> 3, ch = c & 7;
            gload_lds16(Bt + (size_t)(n0 + row) * K + t*64 + ((ch ^ fr3(row)) << 3),
                        dst + (size_t)c * 16);
        }
    };

    // prologue: full tile 0, drain, barrier
    stageA(0, 0); stageA(0, 2); stageB(0, 0); stageB(0, 2);
    vmwait<0>();
    __builtin_amdgcn_s_barrier();
    asm volatile("" ::: "memory");

    for (int t = 0; t < NT; ++t) {
        const bool nl = t + 1 < NT;
        const char* Ab = LB + (t & 1) * 32768;
        const char* Bb = LB + 65536 + (t & 1) * 32768;
        bf16x8 aq[4][2], b0f[2][2], b1f[2][2];

        // ---- ph1: quadrant (m-group 0, n-group 0)
        if (nl) stageA(t+1, 0);
        #pragma unroll
        for (int mm = 0; mm < 4; ++mm) {
            aq[mm][0] = *reinterpret_cast<const bf16x8*>(Ab + aoff[mm]);
            aq[mm][1] = *reinterpret_cast<const bf16x8*>(Ab + (aoff[mm] ^ 64));
        }
        #pragma unroll
        for (int nn = 0; nn < 2; ++nn) {
            b0f[nn][0] = *reinterpret_cast<const bf16x8*>(Bb + boff[nn]);
            b0f[nn][1] = *reinterpret_cast<const bf16x8*>(Bb + (boff[nn] ^ 64));
        }
        __builtin_amdgcn_s_setprio(1);
        #pragma unroll
        for (int kc = 0; kc < 2; ++kc)
            #pragma unroll
            for (int mm = 0; mm < 4; ++mm)
                #pragma unroll
                for (int nn = 0; nn < 2; ++nn)
                    acc[mm][nn] = __builtin_amdgcn_mfma_f32_16x16x32_bf16(
                        aq[mm][kc], b0f[nn][kc], acc[mm][nn], 0, 0, 0);
        __builtin_amdgcn_s_setprio(0);

        // ---- ph2: (0, 1)
        if (nl) stageA(t+1, 2);
        #pragma unroll
        for (int nn = 0; nn < 2; ++nn) {
            b1f[nn][0] = *reinterpret_cast<const bf16x8*>(Bb + boff[2+nn]);
            b1f[nn][1] = *reinterpret_cast<const bf16x8*>(Bb + (boff[2+nn] ^ 64));
        }
        __builtin_amdgcn_s_setprio(1);
        #pragma unroll
        for (int kc = 0; kc < 2; ++kc)
            #pragma unroll
            for (int mm = 0; mm < 4; ++mm)
                #pragma unroll
                for (int nn = 0; nn < 2; ++nn)
                    acc[mm][2+nn] = __builtin_amdgcn_mfma_f32_16x16x32_bf16(
                        aq[mm][kc], b1f[nn][kc], acc[mm][2+nn], 0, 0, 0);
        __builtin_amdgcn_s_setprio(0);

        // ---- ph3: (1, 1)
        if (nl) stageB(t+1, 0);
        #pragma unroll
        for (int mm = 0; mm < 4; ++mm) {
            aq[mm][0] = *reinterpret_cast<const bf16x8*>(Ab + aoff[4+mm]);
            aq[mm][1] = *reinterpret_cast<const bf16x8*>(Ab + (aoff[4+mm] ^ 64));
        }
        __builtin_amdgcn_s_setprio(1);
        #pragma unroll
        for (int kc = 0; kc < 2; ++kc)
            #pragma unroll
            for (int mm = 0; mm < 4; ++mm)
                #pragma unroll
                for (int nn = 0; nn < 2; ++nn)
                    acc[4+mm][2+nn] = __builtin_amdgcn_mfma_f32_16x16x32_bf16(
                        aq[mm][kc], b1f[nn][kc], acc[4+mm][2+nn], 0, 0, 0);
        __builtin_amdgcn_s_setprio(0);

        // ---- ph4: (1, 0) — reuses b0f kept in registers
        if (nl) stageB(t+1, 2);
        __builtin_amdgcn_s_setprio(1);
        #pragma unroll
        for (int kc = 0; kc < 2; ++kc)
            #pragma unroll
            for (int mm = 0; mm < 4; ++mm)
                #pragma unroll
                for (int nn = 0; nn < 2; ++nn)
                    acc[4+mm][nn] = __builtin_amdgcn_mfma_f32_16x16x32_bf16(
                        aq[mm][kc], b0f[nn][kc], acc[4+mm][nn], 0, 0, 0);
        __builtin_amdgcn_s_setprio(0);

        if (nl) {
            vmwait<0>();                        // t+1's 8 loads: issued >=3 phases ago
            __builtin_amdgcn_s_barrier();
            asm volatile("" ::: "memory");
        }
    }

    float bn[4];
    #pragma unroll
    for (int n = 0; n < 4; ++n) bn[n] = bias[n0 + wcol*64 + n*16 + ln15];
    #pragma unroll
    for (int m = 0; m < 8; ++m) {
        #pragma unroll
        for (int j = 0; j < 4; ++j) {
            const int gm = m0 + wrow*128 + m*16 + l4*4 + j;
            #pragma unroll
            for (int n = 0; n < 4; ++n) {
                const int gn = n0 + wcol*64 + n*16 + ln15;
                float v = clip5(0.1f * (acc[m][n][j] + bn[n]));
                float g = 0.5f * v * (1.f + erff(v * 0.70710678118654752f));
                g = clip5(g);
                gout[(size_t)gm * HH + gn] = (__bf16)g;
            }
        }
    }
}

// ---- GEMM2 v3: 256x128, BK=32, ONE barrier per 96-K iteration (128 total).
// B ring-6 (2 iters x 3 powers); As 3 power planes double-buffered (powers
// computed off the MFMA path); counted waits; XCD super-tile swizzle.
__global__ __launch_bounds__(512, 2) void gemm2_k(
    const __bf16* __restrict__ G, const __bf16* __restrict__ Bt,
    const float* __restrict__ bias,
    const float* __restrict__ resid, float* __restrict__ yout)
{
    constexpr int SD    = HH;
    constexpr int K     = 3 * SD;
    constexpr int NIT   = SD / 32;
    constexpr int BN    = 128;
    constexpr int MF    = 4, WN = 2;
    constexpr int BSLOT = BN * 64;                // 8KB
    constexpr int APL   = 16384;
    constexpr int ABUF  = 3 * APL;                // 48KB

    __shared__ char LB[2*ABUF + 6*BSLOT];         // 144KB (size proven in R6)
    char* AsB = LB;
    char* BsB = LB + 2*ABUF;

    const int tid  = threadIdx.x;
    const int lane = tid & 63;
    const int wave = tid >> 6;
    const int wrow = wave / WN, wcol = wave % WN;
    const int b = blockIdx.x, cx = b & 7, q = b >> 3;
    const int m0 = (((cx & 3) << 3) + (q & 7)) * 256;
    const int n0 = (((cx >> 2) << 2) + (q >> 3)) * BN;
    const int ln15 = lane & 15, l4 = lane >> 4;

    int aoff[MF], boff[4];
    #pragma unroll
    for (int m = 0; m < MF; ++m) {
        const int r = wrow*(MF*16) + m*16 + ln15;
        aoff[m] = r*64 + ((l4 ^ frow(r)) << 4);
    }
    #pragma unroll
    for (int n = 0; n < 4; ++n) {
        const int r = wcol*64 + n*16 + ln15;
        boff[n] = r*64 + ((l4 ^ frow(r)) << 4);
    }

    f32x4 acc[MF][4];
    #pragma unroll
    for (int m = 0; m < MF; ++m)
        #pragma unroll
        for (int n = 0; n < 4; ++n)
            acc[m][n] = (f32x4){0.f, 0.f, 0.f, 0.f};

    auto issueB3 = [&](int i, int pb) {
        #pragma unroll
        for (int s = 0; s < 3; ++s) {
            char* dst = BsB + (pb*3 + s) * BSLOT;
            const int kcol = s*SD + 32*i;
            const int row = tid >> 2, ch = tid & 3;
            gload_lds16(Bt + (size_t)(n0 + row) * K + kcol + ((ch ^ frow(row)) << 3),
                        dst + (size_t)tid * 16);
        }
    };

    bf16x8 gw[2];
    auto issueX = [&](int i) {
        #pragma unroll
        for (int k = 0; k < 2; ++k) {
            const int c = k*512 + tid, row = c >> 2, ch = c & 3;
            gw[k] = *reinterpret_cast<const bf16x8*>(
                G + (size_t)(m0 + row) * HH + 32*i + ch*8);
        }
    };

    auto powers = [&](char* Abuf) {
        #pragma unroll
        for (int k = 0; k < 2; ++k) {
            const int c = k*512 + tid, row = c >> 2, ch = c & 3, fr = frow(row);
            bf16x8 u1, u2;
            #pragma unroll
            for (int j = 0; j < 8; ++j) {
                const float v  = (float)gw[k][j];
                const float v2 = v * v;
                u1[j] = (__bf16)v2; u2[j] = (__bf16)(v2 * v);
            }
            const int base = row*64 + ((ch << 4) ^ (fr << 4));
            *reinterpret_cast<bf16x8*>(Abuf +         base) = gw[k];
            *reinterpret_cast<bf16x8*>(Abuf +   APL + base) = u1;
            *reinterpret_cast<bf16x8*>(Abuf + 2*APL + base) = u2;
        }
    };

    auto mfma_phase = [&](const char* Abuf, int p, int slot) {
        const char* As_ = Abuf + p * APL;
        const char* Bs_ = BsB + slot * BSLOT;
        bf16x8 af[MF], bf[4];
        #pragma unroll
        for (int m = 0; m < MF; ++m) af[m] = *reinterpret_cast<const bf16x8*>(As_ + aoff[m]);
        #pragma unroll
        for (int n = 0; n < 4; ++n) bf[n] = *reinterpret_cast<const bf16x8*>(Bs_ + boff[n]);
        __builtin_amdgcn_s_setprio(1);
        #pragma unroll
        for (int m = 0; m < MF; ++m)
            #pragma unroll
            for (int n = 0; n < 4; ++n)
                acc[m][n] = __builtin_amdgcn_mfma_f32_16x16x32_bf16(af[m], bf[n], acc[m][n], 0, 0, 0);
        __builtin_amdgcn_s_setprio(0);
    };

    // prologue: X(0), B3(0)->group0, powers->buf0; drain; barrier
    issueX(0);
    issueB3(0, 0);
    powers(AsB);                                 // compiler waits X only (counted)
    asm volatile("s_waitcnt lgkmcnt(0)" ::: "memory");
    vmwait<0>();
    __builtin_amdgcn_s_barrier();
    asm volatile("" ::: "memory");

    for (int i = 0; i < NIT; ++i) {
        const bool nl = (i + 1 < NIT);
        const int pb = i & 1, qb = (i + 1) & 1;
        if (nl) { issueX(i+1); issueB3(i+1, qb); }
        const char* Ab = AsB + pb * ABUF;
        mfma_phase(Ab, 0, pb*3 + 0);
        mfma_phase(Ab, 1, pb*3 + 1);
        mfma_phase(Ab, 2, pb*3 + 2);
        if (nl) {
            powers(AsB + qb * ABUF);             // waits X(i+1), B3(i+1) in flight
            asm volatile("s_waitcnt lgkmcnt(0)" ::: "memory");
            vmwait<0>();                         // B3(i+1): issued 3 phases ago
            __builtin_amdgcn_s_barrier();
            asm volatile("" ::: "memory");
        }
    }

    float bn[4];
    #pragma unroll
    for (int n = 0; n < 4; ++n) bn[n] = bias[n0 + wcol*64 + n*16 + ln15];
    #pragma unroll
    for (int m = 0; m < MF; ++m) {
        #pragma unroll
        for (int j = 0; j < 4; ++j) {
            const int gm = m0 + wrow*(MF*16) + m*16 + l4*4 + j;
            #pragma unroll
            for (int n = 0; n < 4; ++n) {
                const int gn = n0 + wcol*64 + n*16 + ln15;
                float v = 0.1f * (acc[m][n][j] + bn[n]);
                v = clip5(v);
                yout[(size_t)gm * DD + gn] = v + resid[(size_t)gm * DD + gn];
            }
        }
    }
}

// ---- row LayerNorm over D=1024, in-place, one block per row
__global__ __launch_bounds__(256) void ln_k(float* y,
                                            const float* __restrict__ gamma,
                                            const float* __restrict__ beta) {
    const int t = blockIdx.x, tid = threadIdx.x;
    const float4 v = reinterpret_cast<const float4*>(y + (size_t)t * DD)[tid];
    float s  = v.x + v.y + v.z + v.w;
    float s2 = v.x*v.x + v.y*v.y + v.z*v.z + v.w*v.w;
    #pragma unroll
    for (int off = 32; off > 0; off >>= 1) {
        s  += __shfl_down(s,  off, 64);
        s2 += __shfl_down(s2, off, 64);
    }
    __shared__ float rs[4], rs2[4];
    const int wave = tid >> 6, lane = tid & 63;
    if (lane == 0) { rs[wave] = s; rs2[wave] = s2; }
    __syncthreads();
    s  = rs[0] + rs[1] + rs[2] + rs[3];
    s2 = rs2[0] + rs2[1] + rs2[2] + rs2[3];
    const float mu  = s * (1.f / DD);
    const float var = s2 * (1.f / DD) - mu * mu;
    const float inv = rsqrtf(var + 1e-5f);
    const float4 g = reinterpret_cast<const float4*>(gamma)[tid];
    const float4 b = reinterpret_cast<const float4*>(beta)[tid];
    float4 o;
    o.x = (v.x - mu) * inv * g.x + b.x;
    o.y = (v.y - mu) * inv * g.y + b.y;
    o.z = (v.z - mu) * inv * g.z + b.z;
    o.w = (v.w - mu) * inv * g.w + b.w;
    reinterpret_cast<float4*>(y + (size_t)t * DD)[tid] = o;
}

extern "C" void kernel_launch(void* const* d_in, const int* in_sizes, int n_in,
                              void* d_out, int out_size, void* d_ws, size_t ws_size,
                              hipStream_t stream) {
    const float* x     = (const float*)d_in[0];
    const float* c1    = (const float*)d_in[1];
    const float* c2    = (const float*)d_in[2];
    const float* gamma = (const float*)d_in[3];
    const float* beta  = (const float*)d_in[4];
    float* out = (float*)d_out;
    char* ws = (char*)d_ws;

    // Proven-fitting layout (R11/R12): 142,626,816 B total.
    __bf16* A1    = (__bf16*)(ws + 0);             // [TT][3*DD] bf16 = 50,331,648
    __bf16* gbuf  = (__bf16*)(ws + 50331648);      // [TT][HH]   bf16 = 67,108,864
    ushort* B1p   = (ushort*)(ws + 117440512);     // B1/B2 shared, sequential liveness
    ushort* B2p   = (ushort*)(ws + 117440512);
    float*  bias1 = (float*) (ws + 142606336);
    float*  bias2 = (float*) (ws + 142622720);

    pack_b<DD><<<HH, 256, 0, stream>>>(c1, B1p, bias1);
    pack_a1<<<(TT * DD) / (256 * 8), 256, 0, stream>>>(x, A1);
    gemm1_k<<<512, 512, 0, stream>>>(A1, (const __bf16*)B1p, bias1, gbuf);
    pack_b<HH><<<DD, 256, 0, stream>>>(c2, B2p, bias2);    // B1 dead now
    gemm2_k<<<256, 512, 0, stream>>>(gbuf, (const __bf16*)B2p, bias2, x, (float*)out);
    ln_k<<<TT, 256, 0, stream>>>(out, gamma, beta);
}

// Round 14
// 480.459 us; speedup vs baseline: 1.9718x; 1.0008x over previous
//
#include <hip/hip_runtime.h>
#include <hip/hip_bf16.h>
#include <math.h>

// Problem dims (fixed by the reference)
#define DD 1024
#define HH 4096
#define TT 8192

typedef __attribute__((ext_vector_type(4))) float f32x4;
typedef __attribute__((ext_vector_type(8))) __bf16 bf16x8;

__device__ __forceinline__ ushort f2bf(float f) {
    union { float f; unsigned u; } v; v.f = f;
    unsigned r = v.u + 0x7FFFu + ((v.u >> 16) & 1u);   // RNE
    return (ushort)(r >> 16);
}
__device__ __forceinline__ float clip1(float v){ return fminf(fmaxf(v, -1.f), 1.f); }
__device__ __forceinline__ float clip5(float v){ return fminf(fmaxf(v, -5.f), 5.f); }
__device__ __forceinline__ int frow(int r){ return (r >> 1) & 3; }   // 64B rows

__device__ __forceinline__ void gload_lds16(const void* g, void* l) {
    __builtin_amdgcn_global_load_lds((const __attribute__((address_space(1))) void*)g,
                                     (__attribute__((address_space(3))) void*)l, 16, 0, 0);
}

template<int N> __device__ __forceinline__ void vmwait() {
    if      constexpr (N == 0)  asm volatile("s_waitcnt vmcnt(0)" ::: "memory");
    else if constexpr (N == 4)  asm volatile("s_waitcnt vmcnt(4)" ::: "memory");
    else if constexpr (N == 8)  asm volatile("s_waitcnt vmcnt(8)" ::: "memory");
    else if constexpr (N == 10) asm volatile("s_waitcnt vmcnt(10)" ::: "memory");
}

// ---- pack coeff [N,4,DIN] fp32 -> B^T bf16 [N][3*DIN] (clip); k=0 slice -> bias[N]
template<int DIN>
__global__ __launch_bounds__(256) void pack_b(const float* __restrict__ c,
                                              ushort* __restrict__ Bp,
                                              float* __restrict__ bias) {
    const int n = blockIdx.x;
    const float* src = c + (size_t)n * 4 * DIN;
    ushort* dst = Bp + (size_t)n * 3 * DIN;
    float bsum = 0.f;
    for (int d = threadIdx.x; d < DIN; d += 256) {
        bsum += clip1(src[d]);
        dst[d]         = f2bf(clip1(src[DIN + d]));
        dst[DIN + d]   = f2bf(clip1(src[2*DIN + d]));
        dst[2*DIN + d] = f2bf(clip1(src[3*DIN + d]));
    }
    #pragma unroll
    for (int off = 32; off > 0; off >>= 1) bsum += __shfl_down(bsum, off, 64);
    __shared__ float red[4];
    const int wave = threadIdx.x >> 6, lane = threadIdx.x & 63;
    if (lane == 0) red[wave] = bsum;
    __syncthreads();
    if (threadIdx.x == 0) bias[n] = red[0] + red[1] + red[2] + red[3];
}

// ---- x [T][D] fp32 -> A1 bf16 [T][3*D]: planes (v, v^2, v^3), v = clip5(x)
__global__ __launch_bounds__(256) void pack_a1(const float* __restrict__ x,
                                               __bf16* __restrict__ A1) {
    const int gid = blockIdx.x * 256 + threadIdx.x;   // 8 elems per thread
    const int t = gid >> 7, d0 = (gid & 127) * 8;
    const float* src = x + (size_t)t * DD + d0;
    const f32x4 a = *reinterpret_cast<const f32x4*>(src);
    const f32x4 b = *reinterpret_cast<const f32x4*>(src + 4);
    bf16x8 u0, u1, u2;
    #pragma unroll
    for (int j = 0; j < 4; ++j) {
        float v = clip5(a[j]); float v2 = v*v;
        u0[j] = (__bf16)v; u1[j] = (__bf16)v2; u2[j] = (__bf16)(v2*v);
        v = clip5(b[j]); v2 = v*v;
        u0[j+4] = (__bf16)v; u1[j+4] = (__bf16)v2; u2[j+4] = (__bf16)(v2*v);
    }
    __bf16* dst = A1 + (size_t)t * (3*DD) + d0;
    *reinterpret_cast<bf16x8*>(dst)          = u0;
    *reinterpret_cast<bf16x8*>(dst + DD)     = u1;
    *reinterpret_cast<bf16x8*>(dst + 2*DD)   = u2;
}

// ---- GEMM1 v4: pure bf16 256x256, BK=32, ring-4 lookahead-3 (R12-proven
// ledger), HK-style dual-barrier fine phases: 2 phases/iter, each
// {frag ds_reads -> stage -> counted vmcnt -> bar -> lgkm0 -> 16 MFMA -> bar}.
// XCD 2D super-tile swizzle. Epilogue: *0.1+bias, clip5, gelu, clip5 -> g bf16.
__global__ __launch_bounds__(512, 2) void gemm1_k(
    const __bf16* __restrict__ A, const __bf16* __restrict__ Bt,
    const float* __restrict__ bias, __bf16* __restrict__ gout)
{
    constexpr int K = 3*DD, NT = K/32;          // 96 K-tiles
    constexpr int SLOT = 32768;                 // As 16KB @0, Bs 16KB @16384
    __shared__ char LB[4*SLOT];                 // 128KB ring-4

    const int tid = threadIdx.x, lane = tid & 63, wave = tid >> 6;
    const int wrow = wave >> 2, wcol = wave & 3;        // 2x4 waves, wave tile 128x64
    const int b = blockIdx.x, cx = b & 7, q = b >> 3;   // XCD c owns 8m x 8n panels
    const int m0 = (((cx & 3) << 3) + (q & 7)) * 256;
    const int n0 = (((cx >> 2) << 3) + (q >> 3)) * 256;
    const int ln15 = lane & 15, l4 = lane >> 4;

    int aoff[8], boff[4];
    #pragma unroll
    for (int m = 0; m < 8; ++m) {
        const int r = wrow*128 + m*16 + ln15;
        aoff[m] = r*64 + ((l4 ^ frow(r)) << 4);
    }
    #pragma unroll
    for (int n = 0; n < 4; ++n) {
        const int r = wcol*64 + n*16 + ln15;
        boff[n] = 16384 + r*64 + ((l4 ^ frow(r)) << 4);
    }

    f32x4 acc[8][4];
    #pragma unroll
    for (int m = 0; m < 8; ++m)
        #pragma unroll
        for (int n = 0; n < 4; ++n)
            acc[m][n] = (f32x4){0.f, 0.f, 0.f, 0.f};

    auto stageA = [&](int t) {                  // 2 loads
        char* dst = LB + (t & 3) * SLOT;
        #pragma unroll
        for (int it = 0; it < 2; ++it) {
            const int c = it*512 + tid, row = c >> 2, ch = c & 3;
            gload_lds16(A + (size_t)(m0 + row) * K + t*32 + ((ch ^ frow(row)) << 3),
                        dst + (size_t)c * 16);
        }
    };
    auto stageB = [&](int t) {                  // 2 loads
        char* dst = LB + (t & 3) * SLOT + 16384;
        #pragma unroll
        for (int it = 0; it < 2; ++it) {
            const int c = it*512 + tid, row = c >> 2, ch = c & 3;
            gload_lds16(Bt + (size_t)(n0 + row) * K + t*32 + ((ch ^ frow(row)) << 3),
                        dst + (size_t)c * 16);
        }
    };

    // prologue: tiles 0..2 (12 loads); wait tile0 (leave 8); barrier
    stageA(0); stageB(0); stageA(1); stageB(1); stageA(2); stageB(2);
    vmwait<8>();
    __builtin_amdgcn_s_barrier();
    asm volatile("" ::: "memory");

    for (int t = 0; t < NT; ++t) {
        const char* S = LB + (t & 3) * SLOT;
        bf16x8 af[4], bf[4];

        // ---- phase a: frag reads (A m0-3, B n0-3), stage A(t+3), counted wait
        #pragma unroll
        for (int m = 0; m < 4; ++m) af[m] = *reinterpret_cast<const bf16x8*>(S + aoff[m]);
        #pragma unroll
        for (int n = 0; n < 4; ++n) bf[n] = *reinterpret_cast<const bf16x8*>(S + boff[n]);
        if (t + 3 < NT) { stageA(t+3); vmwait<10>(); }
        else if (t == NT-3) vmwait<8>();
        else if (t == NT-2) vmwait<4>();
        else vmwait<0>();
        __builtin_amdgcn_s_barrier();
        asm volatile("s_waitcnt lgkmcnt(0)" ::: "memory");
        __builtin_amdgcn_s_setprio(1);
        #pragma unroll
        for (int m = 0; m < 4; ++m)
            #pragma unroll
            for (int n = 0; n < 4; ++n)
                acc[m][n] = __builtin_amdgcn_mfma_f32_16x16x32_bf16(af[m], bf[n], acc[m][n], 0, 0, 0);
        __builtin_amdgcn_s_setprio(0);
        __builtin_amdgcn_s_barrier();
        asm volatile("" ::: "memory");

        // ---- phase b: frag reads (A m4-7; B reused in regs), stage B(t+3)
        #pragma unroll
        for (int m = 0; m < 4; ++m) af[m] = *reinterpret_cast<const bf16x8*>(S + aoff[4+m]);
        if (t + 3 < NT) stageB(t+3);
        __builtin_amdgcn_s_barrier();
        asm volatile("s_waitcnt lgkmcnt(0)" ::: "memory");
        __builtin_amdgcn_s_setprio(1);
        #pragma unroll
        for (int m = 0; m < 4; ++m)
            #pragma unroll
            for (int n = 0; n < 4; ++n)
                acc[4+m][n] = __builtin_amdgcn_mfma_f32_16x16x32_bf16(af[m], bf[n], acc[4+m][n], 0, 0, 0);
        __builtin_amdgcn_s_setprio(0);
        __builtin_amdgcn_s_barrier();
        asm volatile("" ::: "memory");
    }

    float bn[4];
    #pragma unroll
    for (int n = 0; n < 4; ++n) bn[n] = bias[n0 + wcol*64 + n*16 + ln15];
    #pragma unroll
    for (int m = 0; m < 8; ++m) {
        #pragma unroll
        for (int j = 0; j < 4; ++j) {
            const int gm = m0 + wrow*128 + m*16 + l4*4 + j;
            #pragma unroll
            for (int n = 0; n < 4; ++n) {
                const int gn = n0 + wcol*64 + n*16 + ln15;
                float v = clip5(0.1f * (acc[m][n][j] + bn[n]));
                float g = 0.5f * v * (1.f + erff(v * 0.70710678118654752f));
                g = clip5(g);
                gout[(size_t)gm * HH + gn] = (__bf16)g;
            }
        }
    }
}

// ---- GEMM2 (R13-proven, 221us): 256x128, BK=32, ONE barrier per 96-K iter.
// B ring-6 (2 iters x 3 powers); As 3 power planes double-buffered; counted
// waits; XCD super-tile swizzle.
__global__ __launch_bounds__(512, 2) void gemm2_k(
    const __bf16* __restrict__ G, const __bf16* __restrict__ Bt,
    const float* __restrict__ bias,
    const float* __restrict__ resid, float* __restrict__ yout)
{
    constexpr int SD    = HH;
    constexpr int K     = 3 * SD;
    constexpr int NIT   = SD / 32;
    constexpr int BN    = 128;
    constexpr int MF    = 4, WN = 2;
    constexpr int BSLOT = BN * 64;                // 8KB
    constexpr int APL   = 16384;
    constexpr int ABUF  = 3 * APL;                // 48KB

    __shared__ char LB[2*ABUF + 6*BSLOT];         // 144KB
    char* AsB = LB;
    char* BsB = LB + 2*ABUF;

    const int tid  = threadIdx.x;
    const int lane = tid & 63;
    const int wave = tid >> 6;
    const int wrow = wave / WN, wcol = wave % WN;
    const int b = blockIdx.x, cx = b & 7, q = b >> 3;
    const int m0 = (((cx & 3) << 3) + (q & 7)) * 256;
    const int n0 = (((cx >> 2) << 2) + (q >> 3)) * BN;
    const int ln15 = lane & 15, l4 = lane >> 4;

    int aoff[MF], boff[4];
    #pragma unroll
    for (int m = 0; m < MF; ++m) {
        const int r = wrow*(MF*16) + m*16 + ln15;
        aoff[m] = r*64 + ((l4 ^ frow(r)) << 4);
    }
    #pragma unroll
    for (int n = 0; n < 4; ++n) {
        const int r = wcol*64 + n*16 + ln15;
        boff[n] = r*64 + ((l4 ^ frow(r)) << 4);
    }

    f32x4 acc[MF][4];
    #pragma unroll
    for (int m = 0; m < MF; ++m)
        #pragma unroll
        for (int n = 0; n < 4; ++n)
            acc[m][n] = (f32x4){0.f, 0.f, 0.f, 0.f};

    auto issueB3 = [&](int i, int pb) {
        #pragma unroll
        for (int s = 0; s < 3; ++s) {
            char* dst = BsB + (pb*3 + s) * BSLOT;
            const int kcol = s*SD + 32*i;
            const int row = tid >> 2, ch = tid & 3;
            gload_lds16(Bt + (size_t)(n0 + row) * K + kcol + ((ch ^ frow(row)) << 3),
                        dst + (size_t)tid * 16);
        }
    };

    bf16x8 gw[2];
    auto issueX = [&](int i) {
        #pragma unroll
        for (int k = 0; k < 2; ++k) {
            const int c = k*512 + tid, row = c >> 2, ch = c & 3;
            gw[k] = *reinterpret_cast<const bf16x8*>(
                G + (size_t)(m0 + row) * HH + 32*i + ch*8);
        }
    };

    auto powers = [&](char* Abuf) {
        #pragma unroll
        for (int k = 0; k < 2; ++k) {
            const int c = k*512 + tid, row = c >> 2, ch = c & 3, fr = frow(row);
            bf16x8 u1, u2;
            #pragma unroll
            for (int j = 0; j < 8; ++j) {
                const float v  = (float)gw[k][j];
                const float v2 = v * v;
                u1[j] = (__bf16)v2; u2[j] = (__bf16)(v2 * v);
            }
            const int base = row*64 + ((ch << 4) ^ (fr << 4));
            *reinterpret_cast<bf16x8*>(Abuf +         base) = gw[k];
            *reinterpret_cast<bf16x8*>(Abuf +   APL + base) = u1;
            *reinterpret_cast<bf16x8*>(Abuf + 2*APL + base) = u2;
        }
    };

    auto mfma_phase = [&](const char* Abuf, int p, int slot) {
        const char* As_ = Abuf + p * APL;
        const char* Bs_ = BsB + slot * BSLOT;
        bf16x8 af[MF], bf[4];
        #pragma unroll
        for (int m = 0; m < MF; ++m) af[m] = *reinterpret_cast<const bf16x8*>(As_ + aoff[m]);
        #pragma unroll
        for (int n = 0; n < 4; ++n) bf[n] = *reinterpret_cast<const bf16x8*>(Bs_ + boff[n]);
        __builtin_amdgcn_s_setprio(1);
        #pragma unroll
        for (int m = 0; m < MF; ++m)
            #pragma unroll
            for (int n = 0; n < 4; ++n)
                acc[m][n] = __builtin_amdgcn_mfma_f32_16x16x32_bf16(af[m], bf[n], acc[m][n], 0, 0, 0);
        __builtin_amdgcn_s_setprio(0);
    };

    issueX(0);
    issueB3(0, 0);
    powers(AsB);
    asm volatile("s_waitcnt lgkmcnt(0)" ::: "memory");
    vmwait<0>();
    __builtin_amdgcn_s_barrier();
    asm volatile("" ::: "memory");

    for (int i = 0; i < NIT; ++i) {
        const bool nl = (i + 1 < NIT);
        const int pb = i & 1, qb = (i + 1) & 1;
        if (nl) { issueX(i+1); issueB3(i+1, qb); }
        const char* Ab = AsB + pb * ABUF;
        mfma_phase(Ab, 0, pb*3 + 0);
        mfma_phase(Ab, 1, pb*3 + 1);
        mfma_phase(Ab, 2, pb*3 + 2);
        if (nl) {
            powers(AsB + qb * ABUF);
            asm volatile("s_waitcnt lgkmcnt(0)" ::: "memory");
            vmwait<0>();
            __builtin_amdgcn_s_barrier();
            asm volatile("" ::: "memory");
        }
    }

    float bn[4];
    #pragma unroll
    for (int n = 0; n < 4; ++n) bn[n] = bias[n0 + wcol*64 + n*16 + ln15];
    #pragma unroll
    for (int m = 0; m < MF; ++m) {
        #pragma unroll
        for (int j = 0; j < 4; ++j) {
            const int gm = m0 + wrow*(MF*16) + m*16 + l4*4 + j;
            #pragma unroll
            for (int n = 0; n < 4; ++n) {
                const int gn = n0 + wcol*64 + n*16 + ln15;
                float v = 0.1f * (acc[m][n][j] + bn[n]);
                v = clip5(v);
                yout[(size_t)gm * DD + gn] = v + resid[(size_t)gm * DD + gn];
            }
        }
    }
}

// ---- row LayerNorm over D=1024, in-place, one block per row
__global__ __launch_bounds__(256) void ln_k(float* y,
                                            const float* __restrict__ gamma,
                                            const float* __restrict__ beta) {
    const int t = blockIdx.x, tid = threadIdx.x;
    const float4 v = reinterpret_cast<const float4*>(y + (size_t)t * DD)[tid];
    float s  = v.x + v.y + v.z + v.w;
    float s2 = v.x*v.x + v.y*v.y + v.z*v.z + v.w*v.w;
    #pragma unroll
    for (int off = 32; off > 0; off >>= 1) {
        s  += __shfl_down(s,  off, 64);
        s2 += __shfl_down(s2, off, 64);
    }
    __shared__ float rs[4], rs2[4];
    const int wave = tid >> 6, lane = tid & 63;
    if (lane == 0) { rs[wave] = s; rs2[wave] = s2; }
    __syncthreads();
    s  = rs[0] + rs[1] + rs[2] + rs[3];
    s2 = rs2[0] + rs2[1] + rs2[2] + rs2[3];
    const float mu  = s * (1.f / DD);
    const float var = s2 * (1.f / DD) - mu * mu;
    const float inv = rsqrtf(var + 1e-5f);
    const float4 g = reinterpret_cast<const float4*>(gamma)[tid];
    const float4 b = reinterpret_cast<const float4*>(beta)[tid];
    float4 o;
    o.x = (v.x - mu) * inv * g.x + b.x;
    o.y = (v.y - mu) * inv * g.y + b.y;
    o.z = (v.z - mu) * inv * g.z + b.z;
    o.w = (v.w - mu) * inv * g.w + b.w;
    reinterpret_cast<float4*>(y + (size_t)t * DD)[tid] = o;
}

extern "C" void kernel_launch(void* const* d_in, const int* in_sizes, int n_in,
                              void* d_out, int out_size, void* d_ws, size_t ws_size,
                              hipStream_t stream) {
    const float* x     = (const float*)d_in[0];
    const float* c1    = (const float*)d_in[1];
    const float* c2    = (const float*)d_in[2];
    const float* gamma = (const float*)d_in[3];
    const float* beta  = (const float*)d_in[4];
    float* out = (float*)d_out;
    char* ws = (char*)d_ws;

    // Proven-fitting layout (R11-R13): 142,626,816 B total.
    __bf16* A1    = (__bf16*)(ws + 0);             // [TT][3*DD] bf16 = 50,331,648
    __bf16* gbuf  = (__bf16*)(ws + 50331648);      // [TT][HH]   bf16 = 67,108,864
    ushort* B1p   = (ushort*)(ws + 117440512);     // B1/B2 shared, sequential liveness
    ushort* B2p   = (ushort*)(ws + 117440512);
    float*  bias1 = (float*) (ws + 142606336);
    float*  bias2 = (float*) (ws + 142622720);

    pack_b<DD><<<HH, 256, 0, stream>>>(c1, B1p, bias1);
    pack_a1<<<(TT * DD) / (256 * 8), 256, 0, stream>>>(x, A1);
    gemm1_k<<<512, 512, 0, stream>>>(A1, (const __bf16*)B1p, bias1, gbuf);
    pack_b<HH><<<DD, 256, 0, stream>>>(c2, B2p, bias2);    // B1 dead now
    gemm2_k<<<256, 512, 0, stream>>>(gbuf, (const __bf16*)B2p, bias2, x, (float*)out);
    ln_k<<<TT, 256, 0, stream>>>(out, gamma, beta);
}